// Round 6
// baseline (2597.164 us; speedup 1.0000x reference)
//
#include <hip/hip_runtime.h>

// Problem constants: B=1, C=2, H=W=64, m=8192, mk=64, K1=K2=36, K3=2, Kc=2592, iters=6 (5 steps).
#define KC 2592
#define KCP 2624           // padded NtT row stride (zeros in tail)
#define HW 4096

// workspace layout (float offsets), total 2818048 floats = 11.27 MB (<= proven 11.29 MB)
#define OFF_L    0u
#define OFF_S    8192u
#define OFF_MT   16384u    // Mt[64][8192]
#define OFF_NTT  540672u   // NtT[64][2624], layout d=(kk*36+ii)*36+jj, cols 2592..2623 zero
#define OFF_BIG  708608u   // Rpart[256][8192] / T1t[256][8192] / (T2part[8][64][2592] + T2sum[64][2592])
#define OFF_GRAM 2805760u  // raw gram 64x64 (shared by Cm and Cn phases)
#define OFF_CMI  2809856u
#define OFF_CNI  2813952u

__global__ __launch_bounds__(256) void k_init(const float* __restrict__ inp, const float* __restrict__ s0,
                                              float* __restrict__ L, float* __restrict__ S,
                                              float* __restrict__ Mt, float* __restrict__ NtT){
  int t = blockIdx.x * 256 + threadIdx.x;
  if (t < 8192){ L[t] = inp[t]; S[t] = s0[t]; }
  if (t < 524288){ int r = t >> 13; int p = t & 8191; Mt[t] = (p == r) ? 1.0f : 0.0f; }
  if (t < 167936){ int r = t / KCP; int d = t - r * KCP;
                   int dr = (r % 36) * 36 + r / 36;   // N0: d=(0*36+ii)*36+jj with col=jj*36+ii=r
                   NtT[t] = (d == dr) ? 1.0f : 0.0f; }
}

// ---- conv_R: Rpart[r+64z][p] = sum_{kk, ii in 9-quarter z, jj} Mt[r][(c+kk)%2][(h+ii)%64][(w+jj)%64] * f[kk][ii][jj]
// 128 thr = 2c x 16h x 4wq; 16 outputs/thread; LDS holds only the 24 needed rows per c.
__global__ __launch_bounds__(128) void k_conv_R(const float* __restrict__ Mtg,
                                                const float* __restrict__ NtT,
                                                float* __restrict__ Rpart){
  __shared__ float img[2][24][68];
  __shared__ float4 filt4[162];
  int r = blockIdx.x, oct = blockIdx.y, z = blockIdx.z, tid = threadIdx.x;
  int rowbase = oct * 16 + z * 9;
  const float4* gi4 = (const float4*)(Mtg + (size_t)r * 8192);
  for (int t = tid; t < 768; t += 128){
    int fw = t & 15, rr = t >> 4;
    int c = (rr >= 24) ? 1 : 0, q = rr - c * 24;
    int gr = (rowbase + q) & 63;
    float4 v4 = gi4[(c * 64 + gr) * 16 + fw];
    float* d = &img[c][q][fw * 4];
    d[0] = v4.x; d[1] = v4.y; d[2] = v4.z; d[3] = v4.w;
  }
  int iilo = z * 9;
  const float* gf = NtT + (size_t)r * KCP;
  for (int t = tid; t < 162; t += 128){
    int kk = t / 81; int rem4 = t - kk * 81;
    filt4[t] = *(const float4*)(gf + kk * 1296 + iilo * 36 + rem4 * 4);
  }
  __syncthreads();
  int c0 = tid >> 6, hl = (tid >> 2) & 15, w0 = (tid & 3) * 16;
  float acc[16];
  #pragma unroll
  for (int u = 0; u < 16; u++) acc[u] = 0.0f;
  #pragma unroll 1
  for (int kk = 0; kk < 2; kk++){
    int cimg = (c0 + kk) & 1;
    #pragma unroll 1
    for (int iix = 0; iix < 9; iix++){
      const float* ib = img[cimg][hl + iix];
      float v[32];
      #pragma unroll
      for (int t = 0; t < 8; t++){
        float4 t4 = *(const float4*)&ib[(w0 + 4 * t) & 63];
        v[4*t] = t4.x; v[4*t+1] = t4.y; v[4*t+2] = t4.z; v[4*t+3] = t4.w;
      }
      const float4* fb = &filt4[kk * 81 + iix * 9];
      #pragma unroll
      for (int g = 0; g < 9; g++){
        float4 ff = fb[g];
        #pragma unroll
        for (int u = 0; u < 16; u++) acc[u] = fmaf(ff.x, v[(4*g + 0 + u) & 31], acc[u]);
        #pragma unroll
        for (int u = 0; u < 16; u++) acc[u] = fmaf(ff.y, v[(4*g + 1 + u) & 31], acc[u]);
        #pragma unroll
        for (int u = 0; u < 16; u++) acc[u] = fmaf(ff.z, v[(4*g + 2 + u) & 31], acc[u]);
        #pragma unroll
        for (int u = 0; u < 16; u++) acc[u] = fmaf(ff.w, v[(4*g + 3 + u) & 31], acc[u]);
        if (g < 5){
          float4 nv = *(const float4*)&ib[(w0 + 32 + 4*g) & 63];
          int s = (4*g) & 31;
          v[s] = nv.x; v[s+1] = nv.y; v[s+2] = nv.z; v[s+3] = nv.w;
        }
      }
    }
  }
  int h = oct * 16 + hl;
  size_t ob = ((size_t)r + 64 * z) * 8192 + (size_t)(c0 * HW + h * 64 + w0);
  *(float4*)&Rpart[ob]      = make_float4(acc[0], acc[1], acc[2], acc[3]);
  *(float4*)&Rpart[ob + 4]  = make_float4(acc[4], acc[5], acc[6], acc[7]);
  *(float4*)&Rpart[ob + 8]  = make_float4(acc[8], acc[9], acc[10], acc[11]);
  *(float4*)&Rpart[ob + 12] = make_float4(acc[12], acc[13], acc[14], acc[15]);
}

// ---- conv_T1: T1t[r+64z][p] = sum L[(c-kk)%2][(h-ii)%64][(w-jj)%64] * f[kk][ii][jj]
__global__ __launch_bounds__(128) void k_conv_T1(const float* __restrict__ Lg,
                                                 const float* __restrict__ NtT,
                                                 float* __restrict__ T1t){
  __shared__ float img[2][24][68];
  __shared__ float4 filt4[162];
  int r = blockIdx.x, oct = blockIdx.y, z = blockIdx.z, tid = threadIdx.x;
  int rowbase = (oct * 16 - z * 9 - 8 + 128) & 63;     // stored q <-> global row (rowbase+q)&63
  const float4* gi4 = (const float4*)Lg;
  for (int t = tid; t < 768; t += 128){
    int fw = t & 15, rr = t >> 4;
    int c = (rr >= 24) ? 1 : 0, q = rr - c * 24;
    int gr = (rowbase + q) & 63;
    float4 v4 = gi4[(c * 64 + gr) * 16 + fw];
    float* d = &img[c][q][fw * 4];
    d[0] = v4.x; d[1] = v4.y; d[2] = v4.z; d[3] = v4.w;
  }
  int iilo = z * 9;
  const float* gf = NtT + (size_t)r * KCP;
  for (int t = tid; t < 162; t += 128){
    int kk = t / 81; int rem4 = t - kk * 81;
    filt4[t] = *(const float4*)(gf + kk * 1296 + iilo * 36 + rem4 * 4);
  }
  __syncthreads();
  int c0 = tid >> 6, hl = (tid >> 2) & 15, w0 = (tid & 3) * 16;
  float acc[16];
  #pragma unroll
  for (int u = 0; u < 16; u++) acc[u] = 0.0f;
  #pragma unroll 1
  for (int kk = 0; kk < 2; kk++){
    int cimg = (c0 - kk + 2) & 1;
    #pragma unroll 1
    for (int iix = 0; iix < 9; iix++){
      const float* ib = img[cimg][hl - iix + 8];       // (h-ii) row
      float v[32];                                     // v[(rel)&31] holds img[w0+rel]
      {
        float4 tm = *(const float4*)&ib[(w0 - 4 + 64) & 63];   // rel -4..-1 -> slots 28..31
        v[28] = tm.x; v[29] = tm.y; v[30] = tm.z; v[31] = tm.w;
      }
      #pragma unroll
      for (int t = 0; t < 4; t++){
        float4 t4 = *(const float4*)&ib[(w0 + 4 * t) & 63];    // rel 0..15
        v[4*t] = t4.x; v[4*t+1] = t4.y; v[4*t+2] = t4.z; v[4*t+3] = t4.w;
      }
      const float4* fb = &filt4[kk * 81 + iix * 9];
      #pragma unroll
      for (int g = 0; g < 9; g++){
        float4 ff = fb[g];
        #pragma unroll
        for (int u = 0; u < 16; u++) acc[u] = fmaf(ff.x, v[(u - (4*g + 0)) & 31], acc[u]);
        #pragma unroll
        for (int u = 0; u < 16; u++) acc[u] = fmaf(ff.y, v[(u - (4*g + 1)) & 31], acc[u]);
        #pragma unroll
        for (int u = 0; u < 16; u++) acc[u] = fmaf(ff.z, v[(u - (4*g + 2)) & 31], acc[u]);
        #pragma unroll
        for (int u = 0; u < 16; u++) acc[u] = fmaf(ff.w, v[(u - (4*g + 3)) & 31], acc[u]);
        if (g < 8){
          float4 nv = *(const float4*)&ib[(w0 - 8 - 4*g + 128) & 63];  // rel -8-4g..-5-4g
          int s = (-8 - 4*g) & 31;
          v[s] = nv.x; v[s+1] = nv.y; v[s+2] = nv.z; v[s+3] = nv.w;
        }
      }
    }
  }
  int h = oct * 16 + hl;
  size_t ob = ((size_t)r + 64 * z) * 8192 + (size_t)(c0 * HW + h * 64 + w0);
  *(float4*)&T1t[ob]      = make_float4(acc[0], acc[1], acc[2], acc[3]);
  *(float4*)&T1t[ob + 4]  = make_float4(acc[4], acc[5], acc[6], acc[7]);
  *(float4*)&T1t[ob + 8]  = make_float4(acc[8], acc[9], acc[10], acc[11]);
  *(float4*)&T1t[ob + 12] = make_float4(acc[12], acc[13], acc[14], acc[15]);
}

// L[p] = clip((inp - S + g*R)/(g+1)); S = (inp - L)/(b+1); R = (1/Kc) * sum_{256 slices} Rpart
// 256 blocks x 256 thr: block owns 32 p; thread sums 32 slices; LDS tree over 8 slice-groups.
__global__ __launch_bounds__(256) void k_reduce_LS(const float* __restrict__ Rpart,
                                                   const float* __restrict__ inp,
                                                   const float* __restrict__ pg, const float* __restrict__ pb,
                                                   float* __restrict__ S, float* __restrict__ Ldst){
  __shared__ float red[8][32];
  int tid = threadIdx.x;
  int pi = tid & 31, sg = tid >> 5;
  int p = blockIdx.x * 32 + pi;
  float acc = 0.0f;
  #pragma unroll 4
  for (int s = sg * 32; s < sg * 32 + 32; s++) acc += Rpart[(size_t)s * 8192 + p];
  red[sg][pi] = acc;
  __syncthreads();
  if (tid < 32){
    float a = 0.0f;
    #pragma unroll
    for (int q = 0; q < 8; q++) a += red[q][pi];
    float R = a * (1.0f / 2592.0f);
    float g = pg[0], b = pb[0];
    float Ln = (inp[p] - S[p] + g * R) / (g + 1.0f);
    Ln = fminf(fmaxf(Ln, 0.0f), 1.0f);
    S[p] = (inp[p] - Ln) / (b + 1.0f);
    Ldst[p] = Ln;
  }
}

// raw gram: out[r1][r2] = dot(rows[r1], rows[r2]) over len4 float4s (row stride in floats)
__global__ __launch_bounds__(64) void k_gram(const float* __restrict__ rows, int stride, int len4,
                                             float* __restrict__ out){
  int e = blockIdx.x; int r1 = e >> 6, r2 = e & 63;
  if (r2 < r1) return;
  int lane = threadIdx.x;
  const float4* a = (const float4*)(rows + (size_t)r1 * stride);
  const float4* b = (const float4*)(rows + (size_t)r2 * stride);
  float acc = 0.0f;
  for (int p = lane; p < len4; p += 64){
    float4 x = a[p], y = b[p];
    acc = fmaf(x.x, y.x, acc); acc = fmaf(x.y, y.y, acc);
    acc = fmaf(x.z, y.z, acc); acc = fmaf(x.w, y.w, acc);
  }
  for (int off = 32; off; off >>= 1) acc += __shfl_down(acc, off, 64);
  if (lane == 0){ out[r1 * 64 + r2] = acc; out[r2 * 64 + r1] = acc; }
}

// dst = inv( 2*g*gram + a*I ) — single-wave in-register Gauss-Jordan (Jordan exchange, SPD,
// no pivoting). Lane c holds column c in b[0..63]. No LDS, no barriers; cross-lane via shfl
// (lane-uniform constant -> v_readlane). ~195 VALU/pivot, fully unrolled.
__global__ __launch_bounds__(64) void k_inv(const float* __restrict__ src,
                                            const float* __restrict__ pg, const float* __restrict__ pa,
                                            float* __restrict__ dst){
  int lane = threadIdx.x;
  float scale = 2.0f * pg[0];
  float ad = pa[0];
  float b[64];
  #pragma unroll
  for (int i = 0; i < 64; i++)
    b[i] = scale * src[i * 64 + lane] + ((i == lane) ? ad : 0.0f);
  #pragma unroll
  for (int k = 0; k < 64; k++){
    float bk = b[k];
    float akk = __shfl(bk, k);
    float p = 1.0f / akk;
    bool isk = (lane == k);
    float t = isk ? 1.0f : bk;      // A[k][c] operand (lane k: virtual 1 on diag)
    float pt = p * t;
    #pragma unroll
    for (int i = 0; i < 64; i++){
      if (i == k) continue;
      float f = __shfl(b[i], k);    // A[i][k], lane-uniform
      float base = isk ? 0.0f : b[i];
      b[i] = fmaf(-f, pt, base);    // lane k: column k = -f*p; else A[i][c] -= f*p*A[k][c]
    }
    b[k] = t * p;                   // lane k: p; else row k scaled: A[k][c]*p
  }
  #pragma unroll
  for (int i = 0; i < 64; i++)
    dst[i * 64 + lane] = b[i];
}

// Mt_new[sbase+s][p] = 2g * sum_{r<64} (sum_z T1t[r+64z][p]) * CmInv[r][sbase+s]
__global__ __launch_bounds__(256) void k_mn(const float* __restrict__ T1t, const float* __restrict__ CmInv,
                                            const float* __restrict__ pg, float* __restrict__ Mt){
  __shared__ float4 ci4[1024];
  int tid = threadIdx.x;
  const float4* g4 = (const float4*)CmInv;
  for (int t = tid; t < 1024; t += 256) ci4[t] = g4[t];
  __syncthreads();
  int p = blockIdx.x * 256 + tid;
  int sbase = blockIdx.y * 32;
  float g2 = 2.0f * pg[0];
  float acc[32];
  #pragma unroll
  for (int s = 0; s < 32; s++) acc[s] = 0.0f;
  for (int r = 0; r < 64; r++){
    float v = T1t[(size_t)r * 8192 + p] + T1t[(size_t)(r + 64) * 8192 + p]
            + T1t[(size_t)(r + 128) * 8192 + p] + T1t[(size_t)(r + 192) * 8192 + p];
    #pragma unroll
    for (int k = 0; k < 8; k++){
      float4 c = ci4[r * 16 + (sbase >> 2) + k];
      acc[4*k+0] = fmaf(v, c.x, acc[4*k+0]);
      acc[4*k+1] = fmaf(v, c.y, acc[4*k+1]);
      acc[4*k+2] = fmaf(v, c.z, acc[4*k+2]);
      acc[4*k+3] = fmaf(v, c.w, acc[4*k+3]);
    }
  }
  #pragma unroll
  for (int s = 0; s < 32; s++) Mt[(size_t)(sbase + s) * 8192 + p] = g2 * acc[s];
}

// T2part[hc][r][col] = sum_{c, h in 8-row chunk hc, w} L[c][h][w] * Mt[r][(c+kk)%2][(h+ii)%64][(w+jj)%64]
__global__ __launch_bounds__(256) void k_conv_T2(const float* __restrict__ Lg,
                                                 const float* __restrict__ Mtg,
                                                 float* __restrict__ T2part){
  __shared__ float Mi[128 * 68];
  __shared__ float4 Ls4[256];
  int r = blockIdx.x, hc = blockIdx.y, tid = threadIdx.x;
  const float4* gm4 = (const float4*)(Mtg + (size_t)r * 8192);
  for (int t = tid; t < 2048; t += 256){
    float4 v4 = gm4[t];
    int row = t >> 4, cb = (t & 15) * 4;
    float* d = &Mi[row * 68 + cb];
    d[0] = v4.x; d[1] = v4.y; d[2] = v4.z; d[3] = v4.w;
  }
  const float4* gl4 = (const float4*)Lg;
  if (tid < 256){
    int c = tid >> 7, rem = tid & 127;
    Ls4[tid] = gl4[c * 1024 + hc * 128 + rem];
  }
  __syncthreads();
  if (tid >= 216) return;
  int kk = tid / 108, rest = tid % 108, ii = rest / 3, jj0 = (rest % 3) * 12;
  float acc[12];
  #pragma unroll
  for (int u = 0; u < 12; u++) acc[u] = 0.0f;
  #pragma unroll 1
  for (int c = 0; c < 2; c++){
    #pragma unroll 1
    for (int hl = 0; hl < 8; hl++){
      int h = hc * 8 + hl;
      const float* ib = &Mi[(((c + kk) & 1) * 64 + ((h + ii) & 63)) * 68];
      const float4* lrow = &Ls4[c * 128 + hl * 16];
      float v[16];
      {
        float4 t0 = *(const float4*)&ib[jj0];
        float4 t1 = *(const float4*)&ib[jj0 + 4];
        float4 t2 = *(const float4*)&ib[jj0 + 8];
        float4 t3 = *(const float4*)&ib[jj0 + 12];
        v[0]=t0.x; v[1]=t0.y; v[2]=t0.z; v[3]=t0.w;
        v[4]=t1.x; v[5]=t1.y; v[6]=t1.z; v[7]=t1.w;
        v[8]=t2.x; v[9]=t2.y; v[10]=t2.z; v[11]=t2.w;
        v[12]=t3.x; v[13]=t3.y; v[14]=t3.z; v[15]=t3.w;
      }
      #pragma unroll
      for (int wg = 0; wg < 16; wg++){
        float4 lv = lrow[wg];
        #pragma unroll
        for (int u = 0; u < 12; u++) acc[u] = fmaf(lv.x, v[(4*wg + 0 + u) & 15], acc[u]);
        #pragma unroll
        for (int u = 0; u < 12; u++) acc[u] = fmaf(lv.y, v[(4*wg + 1 + u) & 15], acc[u]);
        #pragma unroll
        for (int u = 0; u < 12; u++) acc[u] = fmaf(lv.z, v[(4*wg + 2 + u) & 15], acc[u]);
        #pragma unroll
        for (int u = 0; u < 12; u++) acc[u] = fmaf(lv.w, v[(4*wg + 3 + u) & 15], acc[u]);
        if (wg < 15){
          float4 nv = *(const float4*)&ib[(jj0 + 4*wg + 16) & 63];
          int s = (4*wg) & 15;
          v[s] = nv.x; v[s+1] = nv.y; v[s+2] = nv.z; v[s+3] = nv.w;
        }
      }
    }
  }
  #pragma unroll
  for (int u = 0; u < 12; u++){
    int col = kk * 1296 + (jj0 + u) * 36 + ii;
    T2part[((size_t)hc * 64 + r) * KC + col] = acc[u];
  }
}

// T2sum[t] = sum_hc T2part[hc*165888 + t]   (t = r*KC+col)
__global__ __launch_bounds__(256) void k_t2sum(const float* __restrict__ T2part, float* __restrict__ T2sum){
  int t = blockIdx.x * 256 + threadIdx.x;
  float s = 0.0f;
  #pragma unroll
  for (int hc = 0; hc < 8; hc++) s += T2part[(size_t)hc * 165888 + t];
  T2sum[t] = s;
}

// NtT[rr][d(col)] = 2g * sum_s CnInv[s][rr] * T2sum[s][col], rr in 16-chunk per blockIdx.y
__global__ __launch_bounds__(256) void k_nn(const float* __restrict__ T2sum, const float* __restrict__ CnInv,
                                            const float* __restrict__ pg,
                                            float* __restrict__ NtT){
  __shared__ float4 ci4[1024];
  int tid = threadIdx.x;
  const float4* g4 = (const float4*)CnInv;
  for (int t = tid; t < 1024; t += 256) ci4[t] = g4[t];
  __syncthreads();
  int col = blockIdx.x * 256 + tid;
  if (col >= KC) return;
  int rb = blockIdx.y * 16;
  float g2 = 2.0f * pg[0];
  float acc[16];
  #pragma unroll
  for (int rr = 0; rr < 16; rr++) acc[rr] = 0.0f;
  for (int s = 0; s < 64; s++){
    float tv = T2sum[(size_t)s * KC + col];
    #pragma unroll
    for (int k = 0; k < 4; k++){
      float4 c = ci4[s * 16 + (rb >> 2) + k];
      acc[4*k+0] = fmaf(tv, c.x, acc[4*k+0]);
      acc[4*k+1] = fmaf(tv, c.y, acc[4*k+1]);
      acc[4*k+2] = fmaf(tv, c.z, acc[4*k+2]);
      acc[4*k+3] = fmaf(tv, c.w, acc[4*k+3]);
    }
  }
  int kk = col / 1296, rest = col % 1296, jj = rest / 36, iv = rest % 36;
  int d = (kk * 36 + iv) * 36 + jj;
  #pragma unroll
  for (int rr = 0; rr < 16; rr++){
    NtT[(size_t)(rb + rr) * KCP + d] = g2 * acc[rr];
  }
}

extern "C" void kernel_launch(void* const* d_in, const int* in_sizes, int n_in,
                              void* d_out, int out_size, void* d_ws, size_t ws_size,
                              hipStream_t stream) {
  const float* inp = (const float*)d_in[0];
  const float* s0  = (const float*)d_in[1];
  const float* pa  = (const float*)d_in[2];
  const float* pb  = (const float*)d_in[3];
  const float* pg  = (const float*)d_in[4];
  float* ws  = (float*)d_ws;
  float* L   = ws + OFF_L;   float* S   = ws + OFF_S;    float* Mt  = ws + OFF_MT;
  float* NtT = ws + OFF_NTT; float* Big = ws + OFF_BIG;
  float* T2p = ws + OFF_BIG;              // aliased into Big (disjoint lifetimes)
  float* T2s = ws + OFF_BIG + 1327104u;   // aliased into Big
  float* Gr  = ws + OFF_GRAM;
  float* CmI = ws + OFF_CMI; float* CnI = ws + OFF_CNI;
  float* out = (float*)d_out;

  k_init<<<2048, 256, 0, stream>>>(inp, s0, L, S, Mt, NtT);
  for (int step = 0; step < 5; step++){
    k_conv_R<<<dim3(64, 4, 4), 128, 0, stream>>>(Mt, NtT, Big);
    bool last = (step == 4);
    k_reduce_LS<<<256, 256, 0, stream>>>(Big, inp, pg, pb, S, last ? out : L);
    if (last) break;
    k_gram<<<4096, 64, 0, stream>>>(NtT, KCP, KCP / 4, Gr);   // Cm raw = N@N^T (pad zeros)
    k_inv<<<1, 64, 0, stream>>>(Gr, pg, pa, CmI);
    k_conv_T1<<<dim3(64, 4, 4), 128, 0, stream>>>(L, NtT, Big);
    k_mn<<<dim3(32, 2), 256, 0, stream>>>(Big, CmI, pg, Mt);
    k_gram<<<4096, 64, 0, stream>>>(Mt, 8192, 2048, Gr);      // Cn raw = Mn^T@Mn
    k_inv<<<1, 64, 0, stream>>>(Gr, pg, pa, CnI);
    k_conv_T2<<<dim3(64, 8), 256, 0, stream>>>(L, Mt, T2p);
    k_t2sum<<<648, 256, 0, stream>>>(T2p, T2s);
    k_nn<<<dim3(11, 4), 256, 0, stream>>>(T2s, CnI, pg, NtT);
  }
}

// Round 7
// 1728.862 us; speedup vs baseline: 1.5022x; 1.5022x over previous
//
#include <hip/hip_runtime.h>

// Problem constants: B=1, C=2, H=W=64, m=8192, mk=64, K1=K2=36, K3=2, Kc=2592, iters=6 (5 steps).
#define KC 2592
#define KCP 2624           // padded NtT row stride (zeros in tail)
#define HW 4096

// workspace layout (float offsets), total 2818048 floats = 11.27 MB (<= proven 11.29 MB)
#define OFF_L    0u
#define OFF_S    8192u
#define OFF_MT   16384u    // Mt[64][8192]
#define OFF_NTT  540672u   // NtT[64][2624], layout d=(kk*36+ii)*36+jj, cols 2592..2623 zero
#define OFF_BIG  708608u   // Rpart[256][8192] / T1t[256][8192] / (T2part[8][64][2592] + T2sum[64][2592])
#define OFF_GRAM 2805760u  // raw gram 64x64 (shared by Cm and Cn phases)
#define OFF_CMI  2809856u
#define OFF_CNI  2813952u

__global__ __launch_bounds__(256) void k_init(const float* __restrict__ inp, const float* __restrict__ s0,
                                              float* __restrict__ L, float* __restrict__ S,
                                              float* __restrict__ Mt, float* __restrict__ NtT){
  int t = blockIdx.x * 256 + threadIdx.x;
  if (t < 8192){ L[t] = inp[t]; S[t] = s0[t]; }
  if (t < 524288){ int r = t >> 13; int p = t & 8191; Mt[t] = (p == r) ? 1.0f : 0.0f; }
  if (t < 167936){ int r = t / KCP; int d = t - r * KCP;
                   int dr = (r % 36) * 36 + r / 36;   // N0: d=(0*36+ii)*36+jj with col=jj*36+ii=r
                   NtT[t] = (d == dr) ? 1.0f : 0.0f; }
}

// ---- conv_R: Rpart[r+64z][p] = sum_{kk, ii in 9-quarter z, jj} Mt[r][(c+kk)%2][(h+ii)%64][(w+jj)%64] * f[kk][ii][jj]
// 128 thr = 2c x 16h x 4wq; 16 outputs/thread; LDS holds only the 24 needed rows per c.
__global__ __launch_bounds__(128) void k_conv_R(const float* __restrict__ Mtg,
                                                const float* __restrict__ NtT,
                                                float* __restrict__ Rpart){
  __shared__ float img[2][24][68];
  __shared__ float4 filt4[162];
  int r = blockIdx.x, oct = blockIdx.y, z = blockIdx.z, tid = threadIdx.x;
  int rowbase = oct * 16 + z * 9;
  const float4* gi4 = (const float4*)(Mtg + (size_t)r * 8192);
  for (int t = tid; t < 768; t += 128){
    int fw = t & 15, rr = t >> 4;
    int c = (rr >= 24) ? 1 : 0, q = rr - c * 24;
    int gr = (rowbase + q) & 63;
    float4 v4 = gi4[(c * 64 + gr) * 16 + fw];
    float* d = &img[c][q][fw * 4];
    d[0] = v4.x; d[1] = v4.y; d[2] = v4.z; d[3] = v4.w;
  }
  int iilo = z * 9;
  const float* gf = NtT + (size_t)r * KCP;
  for (int t = tid; t < 162; t += 128){
    int kk = t / 81; int rem4 = t - kk * 81;
    filt4[t] = *(const float4*)(gf + kk * 1296 + iilo * 36 + rem4 * 4);
  }
  __syncthreads();
  int c0 = tid >> 6, hl = (tid >> 2) & 15, w0 = (tid & 3) * 16;
  float acc[16];
  #pragma unroll
  for (int u = 0; u < 16; u++) acc[u] = 0.0f;
  #pragma unroll 1
  for (int kk = 0; kk < 2; kk++){
    int cimg = (c0 + kk) & 1;
    #pragma unroll 1
    for (int iix = 0; iix < 9; iix++){
      const float* ib = img[cimg][hl + iix];
      float v[32];
      #pragma unroll
      for (int t = 0; t < 8; t++){
        float4 t4 = *(const float4*)&ib[(w0 + 4 * t) & 63];
        v[4*t] = t4.x; v[4*t+1] = t4.y; v[4*t+2] = t4.z; v[4*t+3] = t4.w;
      }
      const float4* fb = &filt4[kk * 81 + iix * 9];
      #pragma unroll
      for (int g = 0; g < 9; g++){
        float4 ff = fb[g];
        #pragma unroll
        for (int u = 0; u < 16; u++) acc[u] = fmaf(ff.x, v[(4*g + 0 + u) & 31], acc[u]);
        #pragma unroll
        for (int u = 0; u < 16; u++) acc[u] = fmaf(ff.y, v[(4*g + 1 + u) & 31], acc[u]);
        #pragma unroll
        for (int u = 0; u < 16; u++) acc[u] = fmaf(ff.z, v[(4*g + 2 + u) & 31], acc[u]);
        #pragma unroll
        for (int u = 0; u < 16; u++) acc[u] = fmaf(ff.w, v[(4*g + 3 + u) & 31], acc[u]);
        if (g < 5){
          float4 nv = *(const float4*)&ib[(w0 + 32 + 4*g) & 63];
          int s = (4*g) & 31;
          v[s] = nv.x; v[s+1] = nv.y; v[s+2] = nv.z; v[s+3] = nv.w;
        }
      }
    }
  }
  int h = oct * 16 + hl;
  size_t ob = ((size_t)r + 64 * z) * 8192 + (size_t)(c0 * HW + h * 64 + w0);
  *(float4*)&Rpart[ob]      = make_float4(acc[0], acc[1], acc[2], acc[3]);
  *(float4*)&Rpart[ob + 4]  = make_float4(acc[4], acc[5], acc[6], acc[7]);
  *(float4*)&Rpart[ob + 8]  = make_float4(acc[8], acc[9], acc[10], acc[11]);
  *(float4*)&Rpart[ob + 12] = make_float4(acc[12], acc[13], acc[14], acc[15]);
}

// ---- conv_T1: T1t[r+64z][p] = sum L[(c-kk)%2][(h-ii)%64][(w-jj)%64] * f[kk][ii][jj]
__global__ __launch_bounds__(128) void k_conv_T1(const float* __restrict__ Lg,
                                                 const float* __restrict__ NtT,
                                                 float* __restrict__ T1t){
  __shared__ float img[2][24][68];
  __shared__ float4 filt4[162];
  int r = blockIdx.x, oct = blockIdx.y, z = blockIdx.z, tid = threadIdx.x;
  int rowbase = (oct * 16 - z * 9 - 8 + 128) & 63;     // stored q <-> global row (rowbase+q)&63
  const float4* gi4 = (const float4*)Lg;
  for (int t = tid; t < 768; t += 128){
    int fw = t & 15, rr = t >> 4;
    int c = (rr >= 24) ? 1 : 0, q = rr - c * 24;
    int gr = (rowbase + q) & 63;
    float4 v4 = gi4[(c * 64 + gr) * 16 + fw];
    float* d = &img[c][q][fw * 4];
    d[0] = v4.x; d[1] = v4.y; d[2] = v4.z; d[3] = v4.w;
  }
  int iilo = z * 9;
  const float* gf = NtT + (size_t)r * KCP;
  for (int t = tid; t < 162; t += 128){
    int kk = t / 81; int rem4 = t - kk * 81;
    filt4[t] = *(const float4*)(gf + kk * 1296 + iilo * 36 + rem4 * 4);
  }
  __syncthreads();
  int c0 = tid >> 6, hl = (tid >> 2) & 15, w0 = (tid & 3) * 16;
  float acc[16];
  #pragma unroll
  for (int u = 0; u < 16; u++) acc[u] = 0.0f;
  #pragma unroll 1
  for (int kk = 0; kk < 2; kk++){
    int cimg = (c0 - kk + 2) & 1;
    #pragma unroll 1
    for (int iix = 0; iix < 9; iix++){
      const float* ib = img[cimg][hl - iix + 8];       // (h-ii) row
      float v[32];                                     // v[(rel)&31] holds img[w0+rel]
      {
        float4 tm = *(const float4*)&ib[(w0 - 4 + 64) & 63];   // rel -4..-1 -> slots 28..31
        v[28] = tm.x; v[29] = tm.y; v[30] = tm.z; v[31] = tm.w;
      }
      #pragma unroll
      for (int t = 0; t < 4; t++){
        float4 t4 = *(const float4*)&ib[(w0 + 4 * t) & 63];    // rel 0..15
        v[4*t] = t4.x; v[4*t+1] = t4.y; v[4*t+2] = t4.z; v[4*t+3] = t4.w;
      }
      const float4* fb = &filt4[kk * 81 + iix * 9];
      #pragma unroll
      for (int g = 0; g < 9; g++){
        float4 ff = fb[g];
        #pragma unroll
        for (int u = 0; u < 16; u++) acc[u] = fmaf(ff.x, v[(u - (4*g + 0)) & 31], acc[u]);
        #pragma unroll
        for (int u = 0; u < 16; u++) acc[u] = fmaf(ff.y, v[(u - (4*g + 1)) & 31], acc[u]);
        #pragma unroll
        for (int u = 0; u < 16; u++) acc[u] = fmaf(ff.z, v[(u - (4*g + 2)) & 31], acc[u]);
        #pragma unroll
        for (int u = 0; u < 16; u++) acc[u] = fmaf(ff.w, v[(u - (4*g + 3)) & 31], acc[u]);
        if (g < 8){
          float4 nv = *(const float4*)&ib[(w0 - 8 - 4*g + 128) & 63];  // rel -8-4g..-5-4g
          int s = (-8 - 4*g) & 31;
          v[s] = nv.x; v[s+1] = nv.y; v[s+2] = nv.z; v[s+3] = nv.w;
        }
      }
    }
  }
  int h = oct * 16 + hl;
  size_t ob = ((size_t)r + 64 * z) * 8192 + (size_t)(c0 * HW + h * 64 + w0);
  *(float4*)&T1t[ob]      = make_float4(acc[0], acc[1], acc[2], acc[3]);
  *(float4*)&T1t[ob + 4]  = make_float4(acc[4], acc[5], acc[6], acc[7]);
  *(float4*)&T1t[ob + 8]  = make_float4(acc[8], acc[9], acc[10], acc[11]);
  *(float4*)&T1t[ob + 12] = make_float4(acc[12], acc[13], acc[14], acc[15]);
}

// L[p] = clip((inp - S + g*R)/(g+1)); S = (inp - L)/(b+1); R = (1/Kc) * sum_{256 slices} Rpart
// 256 blocks x 256 thr: block owns 32 p; thread sums 32 slices; LDS tree over 8 slice-groups.
__global__ __launch_bounds__(256) void k_reduce_LS(const float* __restrict__ Rpart,
                                                   const float* __restrict__ inp,
                                                   const float* __restrict__ pg, const float* __restrict__ pb,
                                                   float* __restrict__ S, float* __restrict__ Ldst){
  __shared__ float red[8][32];
  int tid = threadIdx.x;
  int pi = tid & 31, sg = tid >> 5;
  int p = blockIdx.x * 32 + pi;
  float acc = 0.0f;
  #pragma unroll 4
  for (int s = sg * 32; s < sg * 32 + 32; s++) acc += Rpart[(size_t)s * 8192 + p];
  red[sg][pi] = acc;
  __syncthreads();
  if (tid < 32){
    float a = 0.0f;
    #pragma unroll
    for (int q = 0; q < 8; q++) a += red[q][pi];
    float R = a * (1.0f / 2592.0f);
    float g = pg[0], b = pb[0];
    float Ln = (inp[p] - S[p] + g * R) / (g + 1.0f);
    Ln = fminf(fmaxf(Ln, 0.0f), 1.0f);
    S[p] = (inp[p] - Ln) / (b + 1.0f);
    Ldst[p] = Ln;
  }
}

// raw gram: out[r1][r2] = dot(rows[r1], rows[r2]) over len4 float4s (row stride in floats)
__global__ __launch_bounds__(64) void k_gram(const float* __restrict__ rows, int stride, int len4,
                                             float* __restrict__ out){
  int e = blockIdx.x; int r1 = e >> 6, r2 = e & 63;
  if (r2 < r1) return;
  int lane = threadIdx.x;
  const float4* a = (const float4*)(rows + (size_t)r1 * stride);
  const float4* b = (const float4*)(rows + (size_t)r2 * stride);
  float acc = 0.0f;
  for (int p = lane; p < len4; p += 64){
    float4 x = a[p], y = b[p];
    acc = fmaf(x.x, y.x, acc); acc = fmaf(x.y, y.y, acc);
    acc = fmaf(x.z, y.z, acc); acc = fmaf(x.w, y.w, acc);
  }
  for (int off = 32; off; off >>= 1) acc += __shfl_down(acc, off, 64);
  if (lane == 0){ out[r1 * 64 + r2] = acc; out[r2 * 64 + r1] = acc; }
}

// ---- k_inv: dst = inv( 2*g*gram + a*I ) — single-wave in-register Jordan exchange (SPD, no
// pivoting). Lane c holds column c in b[0..63]. Pivot index K is a TEMPLATE parameter so every
// b[] index is a parse-time constant -> SROA keeps b[] in VGPRs (R5's loop-var b[k] blocked
// SROA and spilled the whole array to scratch: VGPR_Count=40, 236 us). No LDS, no barriers.
template<int K>
__device__ __forceinline__ void gj_step(float (&b)[64], int lane){
  float bk = b[K];
  float akk = __shfl(bk, K);             // A[K][K], lane-uniform -> v_readlane
  float p = 1.0f / akk;
  bool isk = (lane == K);
  float t = isk ? 1.0f : bk;             // A[K][c] operand (lane K: virtual 1 on diag)
  float pt = p * t;
  #pragma unroll
  for (int i = 0; i < 64; i++){
    if (i == K) continue;                // compile-time elision
    float f = __shfl(b[i], K);           // A[i][K], lane-uniform
    float base = isk ? 0.0f : b[i];
    b[i] = fmaf(-f, pt, base);           // lane K: column K = -f*p; else A[i][c] -= f*pt
  }
  b[K] = t * p;                          // lane K: p; else row K scaled
}
template<int K> struct GJ {
  static __device__ __forceinline__ void run(float (&b)[64], int lane){
    gj_step<K>(b, lane);
    GJ<K + 1>::run(b, lane);
  }
};
template<> struct GJ<64> {
  static __device__ __forceinline__ void run(float (&b)[64], int lane){}
};

__global__ __launch_bounds__(64) void k_inv(const float* __restrict__ src,
                                            const float* __restrict__ pg, const float* __restrict__ pa,
                                            float* __restrict__ dst){
  int lane = threadIdx.x;
  float scale = 2.0f * pg[0];
  float ad = pa[0];
  float b[64];
  #pragma unroll
  for (int i = 0; i < 64; i++)
    b[i] = scale * src[i * 64 + lane] + ((i == lane) ? ad : 0.0f);
  GJ<0>::run(b, lane);
  #pragma unroll
  for (int i = 0; i < 64; i++)
    dst[i * 64 + lane] = b[i];
}

// Mt_new[sbase+s][p] = 2g * sum_{r<64} (sum_z T1t[r+64z][p]) * CmInv[r][sbase+s]
__global__ __launch_bounds__(256) void k_mn(const float* __restrict__ T1t, const float* __restrict__ CmInv,
                                            const float* __restrict__ pg, float* __restrict__ Mt){
  __shared__ float4 ci4[1024];
  int tid = threadIdx.x;
  const float4* g4 = (const float4*)CmInv;
  for (int t = tid; t < 1024; t += 256) ci4[t] = g4[t];
  __syncthreads();
  int p = blockIdx.x * 256 + tid;
  int sbase = blockIdx.y * 32;
  float g2 = 2.0f * pg[0];
  float acc[32];
  #pragma unroll
  for (int s = 0; s < 32; s++) acc[s] = 0.0f;
  for (int r = 0; r < 64; r++){
    float v = T1t[(size_t)r * 8192 + p] + T1t[(size_t)(r + 64) * 8192 + p]
            + T1t[(size_t)(r + 128) * 8192 + p] + T1t[(size_t)(r + 192) * 8192 + p];
    #pragma unroll
    for (int k = 0; k < 8; k++){
      float4 c = ci4[r * 16 + (sbase >> 2) + k];
      acc[4*k+0] = fmaf(v, c.x, acc[4*k+0]);
      acc[4*k+1] = fmaf(v, c.y, acc[4*k+1]);
      acc[4*k+2] = fmaf(v, c.z, acc[4*k+2]);
      acc[4*k+3] = fmaf(v, c.w, acc[4*k+3]);
    }
  }
  #pragma unroll
  for (int s = 0; s < 32; s++) Mt[(size_t)(sbase + s) * 8192 + p] = g2 * acc[s];
}

// T2part[hc][r][col] = sum_{c, h in 8-row chunk hc, w} L[c][h][w] * Mt[r][(c+kk)%2][(h+ii)%64][(w+jj)%64]
__global__ __launch_bounds__(256) void k_conv_T2(const float* __restrict__ Lg,
                                                 const float* __restrict__ Mtg,
                                                 float* __restrict__ T2part){
  __shared__ float Mi[128 * 68];
  __shared__ float4 Ls4[256];
  int r = blockIdx.x, hc = blockIdx.y, tid = threadIdx.x;
  const float4* gm4 = (const float4*)(Mtg + (size_t)r * 8192);
  for (int t = tid; t < 2048; t += 256){
    float4 v4 = gm4[t];
    int row = t >> 4, cb = (t & 15) * 4;
    float* d = &Mi[row * 68 + cb];
    d[0] = v4.x; d[1] = v4.y; d[2] = v4.z; d[3] = v4.w;
  }
  const float4* gl4 = (const float4*)Lg;
  if (tid < 256){
    int c = tid >> 7, rem = tid & 127;
    Ls4[tid] = gl4[c * 1024 + hc * 128 + rem];
  }
  __syncthreads();
  if (tid >= 216) return;
  int kk = tid / 108, rest = tid % 108, ii = rest / 3, jj0 = (rest % 3) * 12;
  float acc[12];
  #pragma unroll
  for (int u = 0; u < 12; u++) acc[u] = 0.0f;
  #pragma unroll 1
  for (int c = 0; c < 2; c++){
    #pragma unroll 1
    for (int hl = 0; hl < 8; hl++){
      int h = hc * 8 + hl;
      const float* ib = &Mi[(((c + kk) & 1) * 64 + ((h + ii) & 63)) * 68];
      const float4* lrow = &Ls4[c * 128 + hl * 16];
      float v[16];
      {
        float4 t0 = *(const float4*)&ib[jj0];
        float4 t1 = *(const float4*)&ib[jj0 + 4];
        float4 t2 = *(const float4*)&ib[jj0 + 8];
        float4 t3 = *(const float4*)&ib[jj0 + 12];
        v[0]=t0.x; v[1]=t0.y; v[2]=t0.z; v[3]=t0.w;
        v[4]=t1.x; v[5]=t1.y; v[6]=t1.z; v[7]=t1.w;
        v[8]=t2.x; v[9]=t2.y; v[10]=t2.z; v[11]=t2.w;
        v[12]=t3.x; v[13]=t3.y; v[14]=t3.z; v[15]=t3.w;
      }
      #pragma unroll
      for (int wg = 0; wg < 16; wg++){
        float4 lv = lrow[wg];
        #pragma unroll
        for (int u = 0; u < 12; u++) acc[u] = fmaf(lv.x, v[(4*wg + 0 + u) & 15], acc[u]);
        #pragma unroll
        for (int u = 0; u < 12; u++) acc[u] = fmaf(lv.y, v[(4*wg + 1 + u) & 15], acc[u]);
        #pragma unroll
        for (int u = 0; u < 12; u++) acc[u] = fmaf(lv.z, v[(4*wg + 2 + u) & 15], acc[u]);
        #pragma unroll
        for (int u = 0; u < 12; u++) acc[u] = fmaf(lv.w, v[(4*wg + 3 + u) & 15], acc[u]);
        if (wg < 15){
          float4 nv = *(const float4*)&ib[(jj0 + 4*wg + 16) & 63];
          int s = (4*wg) & 15;
          v[s] = nv.x; v[s+1] = nv.y; v[s+2] = nv.z; v[s+3] = nv.w;
        }
      }
    }
  }
  #pragma unroll
  for (int u = 0; u < 12; u++){
    int col = kk * 1296 + (jj0 + u) * 36 + ii;
    T2part[((size_t)hc * 64 + r) * KC + col] = acc[u];
  }
}

// T2sum[t] = sum_hc T2part[hc*165888 + t]   (t = r*KC+col)
__global__ __launch_bounds__(256) void k_t2sum(const float* __restrict__ T2part, float* __restrict__ T2sum){
  int t = blockIdx.x * 256 + threadIdx.x;
  float s = 0.0f;
  #pragma unroll
  for (int hc = 0; hc < 8; hc++) s += T2part[(size_t)hc * 165888 + t];
  T2sum[t] = s;
}

// NtT[rr][d(col)] = 2g * sum_s CnInv[s][rr] * T2sum[s][col], rr in 16-chunk per blockIdx.y
__global__ __launch_bounds__(256) void k_nn(const float* __restrict__ T2sum, const float* __restrict__ CnInv,
                                            const float* __restrict__ pg,
                                            float* __restrict__ NtT){
  __shared__ float4 ci4[1024];
  int tid = threadIdx.x;
  const float4* g4 = (const float4*)CnInv;
  for (int t = tid; t < 1024; t += 256) ci4[t] = g4[t];
  __syncthreads();
  int col = blockIdx.x * 256 + tid;
  if (col >= KC) return;
  int rb = blockIdx.y * 16;
  float g2 = 2.0f * pg[0];
  float acc[16];
  #pragma unroll
  for (int rr = 0; rr < 16; rr++) acc[rr] = 0.0f;
  for (int s = 0; s < 64; s++){
    float tv = T2sum[(size_t)s * KC + col];
    #pragma unroll
    for (int k = 0; k < 4; k++){
      float4 c = ci4[s * 16 + (rb >> 2) + k];
      acc[4*k+0] = fmaf(tv, c.x, acc[4*k+0]);
      acc[4*k+1] = fmaf(tv, c.y, acc[4*k+1]);
      acc[4*k+2] = fmaf(tv, c.z, acc[4*k+2]);
      acc[4*k+3] = fmaf(tv, c.w, acc[4*k+3]);
    }
  }
  int kk = col / 1296, rest = col % 1296, jj = rest / 36, iv = rest % 36;
  int d = (kk * 36 + iv) * 36 + jj;
  #pragma unroll
  for (int rr = 0; rr < 16; rr++){
    NtT[(size_t)(rb + rr) * KCP + d] = g2 * acc[rr];
  }
}

extern "C" void kernel_launch(void* const* d_in, const int* in_sizes, int n_in,
                              void* d_out, int out_size, void* d_ws, size_t ws_size,
                              hipStream_t stream) {
  const float* inp = (const float*)d_in[0];
  const float* s0  = (const float*)d_in[1];
  const float* pa  = (const float*)d_in[2];
  const float* pb  = (const float*)d_in[3];
  const float* pg  = (const float*)d_in[4];
  float* ws  = (float*)d_ws;
  float* L   = ws + OFF_L;   float* S   = ws + OFF_S;    float* Mt  = ws + OFF_MT;
  float* NtT = ws + OFF_NTT; float* Big = ws + OFF_BIG;
  float* T2p = ws + OFF_BIG;              // aliased into Big (disjoint lifetimes)
  float* T2s = ws + OFF_BIG + 1327104u;   // aliased into Big
  float* Gr  = ws + OFF_GRAM;
  float* CmI = ws + OFF_CMI; float* CnI = ws + OFF_CNI;
  float* out = (float*)d_out;

  k_init<<<2048, 256, 0, stream>>>(inp, s0, L, S, Mt, NtT);
  for (int step = 0; step < 5; step++){
    k_conv_R<<<dim3(64, 4, 4), 128, 0, stream>>>(Mt, NtT, Big);
    bool last = (step == 4);
    k_reduce_LS<<<256, 256, 0, stream>>>(Big, inp, pg, pb, S, last ? out : L);
    if (last) break;
    k_gram<<<4096, 64, 0, stream>>>(NtT, KCP, KCP / 4, Gr);   // Cm raw = N@N^T (pad zeros)
    k_inv<<<1, 64, 0, stream>>>(Gr, pg, pa, CmI);
    k_conv_T1<<<dim3(64, 4, 4), 128, 0, stream>>>(L, NtT, Big);
    k_mn<<<dim3(32, 2), 256, 0, stream>>>(Big, CmI, pg, Mt);
    k_gram<<<4096, 64, 0, stream>>>(Mt, 8192, 2048, Gr);      // Cn raw = Mn^T@Mn
    k_inv<<<1, 64, 0, stream>>>(Gr, pg, pa, CnI);
    k_conv_T2<<<dim3(64, 8), 256, 0, stream>>>(L, Mt, T2p);
    k_t2sum<<<648, 256, 0, stream>>>(T2p, T2s);
    k_nn<<<dim3(11, 4), 256, 0, stream>>>(T2s, CnI, pg, NtT);
  }
}

// Round 8
// 987.608 us; speedup vs baseline: 2.6298x; 1.7506x over previous
//
#include <hip/hip_runtime.h>

// Problem constants: B=1, C=2, H=W=64, m=8192, mk=64, K1=K2=36, K3=2, Kc=2592, iters=6 (5 steps).
#define KC 2592
#define KCP 2624           // padded NtT row stride (zeros in tail)
#define HW 4096

// workspace layout (float offsets), total 2818048 floats = 11.27 MB (<= proven 11.29 MB)
#define OFF_L    0u
#define OFF_S    8192u
#define OFF_MT   16384u    // Mt[64][8192]
#define OFF_NTT  540672u   // NtT[64][2624], layout d=(kk*36+ii)*36+jj, cols 2592..2623 zero
#define OFF_BIG  708608u   // Rpart[256][8192] / T1t[256][8192] / (T2part[8][64][2592] + T2sum[64][2592])
#define OFF_GRAM 2805760u  // raw gram 64x64 (shared by Cm and Cn phases)
#define OFF_CMI  2809856u
#define OFF_CNI  2813952u

__global__ __launch_bounds__(256) void k_init(const float* __restrict__ inp, const float* __restrict__ s0,
                                              float* __restrict__ L, float* __restrict__ S,
                                              float* __restrict__ Mt, float* __restrict__ NtT){
  int t = blockIdx.x * 256 + threadIdx.x;
  if (t < 8192){ L[t] = inp[t]; S[t] = s0[t]; }
  if (t < 524288){ int r = t >> 13; int p = t & 8191; Mt[t] = (p == r) ? 1.0f : 0.0f; }
  if (t < 167936){ int r = t / KCP; int d = t - r * KCP;
                   int dr = (r % 36) * 36 + r / 36;   // N0: d=(0*36+ii)*36+jj with col=jj*36+ii=r
                   NtT[t] = (d == dr) ? 1.0f : 0.0f; }
}

// ---- in-register Jordan-exchange inverse of (2g*gram + a*I), SPD, no pivoting.
// Lane c holds column c in b[0..63] (template-constant indices -> SROA keeps b[] in VGPRs;
// verified VGPR_Count=72 in R6). Cross-lane via v_readlane (VALU) NOT __shfl/ds_bpermute
// (R6: 4096 ds_bpermute = DS-pipe latency chain at droop clock = 230 us). Designed to run as
// ONE sentinel wave fused into a big conv launch so the chain runs at boost clock, hidden.
__device__ __forceinline__ float readlane_f(float x, int lane){
  return __uint_as_float(__builtin_amdgcn_readlane(__float_as_uint(x), lane));
}
template<int K>
__device__ __forceinline__ void gj_step(float (&b)[64], int lane){
  float bk = b[K];
  float akk = readlane_f(bk, K);         // A[K][K], uniform (SGPR)
  float p = 1.0f / akk;
  bool isk = (lane == K);
  float t = isk ? 1.0f : bk;             // A[K][c] operand (lane K: virtual 1 on diag)
  float pt = p * t;
  #pragma unroll
  for (int i = 0; i < 64; i++){
    if (i == K) continue;                // compile-time elision
    float f = readlane_f(b[i], K);       // A[i][K], uniform (SGPR operand to fma)
    float base = isk ? 0.0f : b[i];
    b[i] = fmaf(-f, pt, base);           // lane K: column K = -f*p; else A[i][c] -= f*pt
  }
  b[K] = t * p;                          // lane K: p; else row K scaled
}
template<int K> struct GJ {
  static __device__ __forceinline__ void run(float (&b)[64], int lane){
    gj_step<K>(b, lane);
    GJ<K + 1>::run(b, lane);
  }
};
template<> struct GJ<64> {
  static __device__ __forceinline__ void run(float (&b)[64], int lane){}
};
__device__ void inv64(const float* __restrict__ src, const float* __restrict__ pg,
                      const float* __restrict__ pa, float* __restrict__ dst, int lane){
  float scale = 2.0f * pg[0];
  float ad = pa[0];
  float b[64];
  #pragma unroll
  for (int i = 0; i < 64; i++)
    b[i] = scale * src[i * 64 + lane] + ((i == lane) ? ad : 0.0f);
  GJ<0>::run(b, lane);
  #pragma unroll
  for (int i = 0; i < 64; i++)
    dst[i * 64 + lane] = b[i];
}

// ---- conv_R: Rpart[r+64z][p] = sum_{kk, ii in 9-quarter z, jj} Mt[r][(c+kk)%2][(h+ii)%64][(w+jj)%64] * f[kk][ii][jj]
// 128 thr = 2c x 16h x 4wq; 16 outputs/thread; LDS holds only the 24 needed rows per c.
__global__ __launch_bounds__(128) void k_conv_R(const float* __restrict__ Mtg,
                                                const float* __restrict__ NtT,
                                                float* __restrict__ Rpart){
  __shared__ float img[2][24][68];
  __shared__ float4 filt4[162];
  int r = blockIdx.x, oct = blockIdx.y, z = blockIdx.z, tid = threadIdx.x;
  int rowbase = oct * 16 + z * 9;
  const float4* gi4 = (const float4*)(Mtg + (size_t)r * 8192);
  for (int t = tid; t < 768; t += 128){
    int fw = t & 15, rr = t >> 4;
    int c = (rr >= 24) ? 1 : 0, q = rr - c * 24;
    int gr = (rowbase + q) & 63;
    float4 v4 = gi4[(c * 64 + gr) * 16 + fw];
    float* d = &img[c][q][fw * 4];
    d[0] = v4.x; d[1] = v4.y; d[2] = v4.z; d[3] = v4.w;
  }
  int iilo = z * 9;
  const float* gf = NtT + (size_t)r * KCP;
  for (int t = tid; t < 162; t += 128){
    int kk = t / 81; int rem4 = t - kk * 81;
    filt4[t] = *(const float4*)(gf + kk * 1296 + iilo * 36 + rem4 * 4);
  }
  __syncthreads();
  int c0 = tid >> 6, hl = (tid >> 2) & 15, w0 = (tid & 3) * 16;
  float acc[16];
  #pragma unroll
  for (int u = 0; u < 16; u++) acc[u] = 0.0f;
  #pragma unroll 1
  for (int kk = 0; kk < 2; kk++){
    int cimg = (c0 + kk) & 1;
    #pragma unroll 1
    for (int iix = 0; iix < 9; iix++){
      const float* ib = img[cimg][hl + iix];
      float v[32];
      #pragma unroll
      for (int t = 0; t < 8; t++){
        float4 t4 = *(const float4*)&ib[(w0 + 4 * t) & 63];
        v[4*t] = t4.x; v[4*t+1] = t4.y; v[4*t+2] = t4.z; v[4*t+3] = t4.w;
      }
      const float4* fb = &filt4[kk * 81 + iix * 9];
      #pragma unroll
      for (int g = 0; g < 9; g++){
        float4 ff = fb[g];
        #pragma unroll
        for (int u = 0; u < 16; u++) acc[u] = fmaf(ff.x, v[(4*g + 0 + u) & 31], acc[u]);
        #pragma unroll
        for (int u = 0; u < 16; u++) acc[u] = fmaf(ff.y, v[(4*g + 1 + u) & 31], acc[u]);
        #pragma unroll
        for (int u = 0; u < 16; u++) acc[u] = fmaf(ff.z, v[(4*g + 2 + u) & 31], acc[u]);
        #pragma unroll
        for (int u = 0; u < 16; u++) acc[u] = fmaf(ff.w, v[(4*g + 3 + u) & 31], acc[u]);
        if (g < 5){
          float4 nv = *(const float4*)&ib[(w0 + 32 + 4*g) & 63];
          int s = (4*g) & 31;
          v[s] = nv.x; v[s+1] = nv.y; v[s+2] = nv.z; v[s+3] = nv.w;
        }
      }
    }
  }
  int h = oct * 16 + hl;
  size_t ob = ((size_t)r + 64 * z) * 8192 + (size_t)(c0 * HW + h * 64 + w0);
  *(float4*)&Rpart[ob]      = make_float4(acc[0], acc[1], acc[2], acc[3]);
  *(float4*)&Rpart[ob + 4]  = make_float4(acc[4], acc[5], acc[6], acc[7]);
  *(float4*)&Rpart[ob + 8]  = make_float4(acc[8], acc[9], acc[10], acc[11]);
  *(float4*)&Rpart[ob + 12] = make_float4(acc[12], acc[13], acc[14], acc[15]);
}

// ---- conv_T1 (+ fused inv(Cm) as sentinel z==4): T1t[r+64z][p] = sum L[...] * f[kk][ii][jj]
__global__ __launch_bounds__(128) void k_conv_T1(const float* __restrict__ Lg,
                                                 const float* __restrict__ NtT,
                                                 float* __restrict__ T1t,
                                                 const float* __restrict__ Gr,
                                                 const float* __restrict__ pg,
                                                 const float* __restrict__ pa,
                                                 float* __restrict__ CmI){
  __shared__ float img[2][24][68];
  __shared__ float4 filt4[162];
  if (blockIdx.z == 4){
    if (blockIdx.x == 0 && blockIdx.y == 0 && threadIdx.x < 64)
      inv64(Gr, pg, pa, CmI, threadIdx.x);
    return;
  }
  int r = blockIdx.x, oct = blockIdx.y, z = blockIdx.z, tid = threadIdx.x;
  int rowbase = (oct * 16 - z * 9 - 8 + 128) & 63;     // stored q <-> global row (rowbase+q)&63
  const float4* gi4 = (const float4*)Lg;
  for (int t = tid; t < 768; t += 128){
    int fw = t & 15, rr = t >> 4;
    int c = (rr >= 24) ? 1 : 0, q = rr - c * 24;
    int gr = (rowbase + q) & 63;
    float4 v4 = gi4[(c * 64 + gr) * 16 + fw];
    float* d = &img[c][q][fw * 4];
    d[0] = v4.x; d[1] = v4.y; d[2] = v4.z; d[3] = v4.w;
  }
  int iilo = z * 9;
  const float* gf = NtT + (size_t)r * KCP;
  for (int t = tid; t < 162; t += 128){
    int kk = t / 81; int rem4 = t - kk * 81;
    filt4[t] = *(const float4*)(gf + kk * 1296 + iilo * 36 + rem4 * 4);
  }
  __syncthreads();
  int c0 = tid >> 6, hl = (tid >> 2) & 15, w0 = (tid & 3) * 16;
  float acc[16];
  #pragma unroll
  for (int u = 0; u < 16; u++) acc[u] = 0.0f;
  #pragma unroll 1
  for (int kk = 0; kk < 2; kk++){
    int cimg = (c0 - kk + 2) & 1;
    #pragma unroll 1
    for (int iix = 0; iix < 9; iix++){
      const float* ib = img[cimg][hl - iix + 8];       // (h-ii) row
      float v[32];                                     // v[(rel)&31] holds img[w0+rel]
      {
        float4 tm = *(const float4*)&ib[(w0 - 4 + 64) & 63];   // rel -4..-1 -> slots 28..31
        v[28] = tm.x; v[29] = tm.y; v[30] = tm.z; v[31] = tm.w;
      }
      #pragma unroll
      for (int t = 0; t < 4; t++){
        float4 t4 = *(const float4*)&ib[(w0 + 4 * t) & 63];    // rel 0..15
        v[4*t] = t4.x; v[4*t+1] = t4.y; v[4*t+2] = t4.z; v[4*t+3] = t4.w;
      }
      const float4* fb = &filt4[kk * 81 + iix * 9];
      #pragma unroll
      for (int g = 0; g < 9; g++){
        float4 ff = fb[g];
        #pragma unroll
        for (int u = 0; u < 16; u++) acc[u] = fmaf(ff.x, v[(u - (4*g + 0)) & 31], acc[u]);
        #pragma unroll
        for (int u = 0; u < 16; u++) acc[u] = fmaf(ff.y, v[(u - (4*g + 1)) & 31], acc[u]);
        #pragma unroll
        for (int u = 0; u < 16; u++) acc[u] = fmaf(ff.z, v[(u - (4*g + 2)) & 31], acc[u]);
        #pragma unroll
        for (int u = 0; u < 16; u++) acc[u] = fmaf(ff.w, v[(u - (4*g + 3)) & 31], acc[u]);
        if (g < 8){
          float4 nv = *(const float4*)&ib[(w0 - 8 - 4*g + 128) & 63];  // rel -8-4g..-5-4g
          int s = (-8 - 4*g) & 31;
          v[s] = nv.x; v[s+1] = nv.y; v[s+2] = nv.z; v[s+3] = nv.w;
        }
      }
    }
  }
  int h = oct * 16 + hl;
  size_t ob = ((size_t)r + 64 * z) * 8192 + (size_t)(c0 * HW + h * 64 + w0);
  *(float4*)&T1t[ob]      = make_float4(acc[0], acc[1], acc[2], acc[3]);
  *(float4*)&T1t[ob + 4]  = make_float4(acc[4], acc[5], acc[6], acc[7]);
  *(float4*)&T1t[ob + 8]  = make_float4(acc[8], acc[9], acc[10], acc[11]);
  *(float4*)&T1t[ob + 12] = make_float4(acc[12], acc[13], acc[14], acc[15]);
}

// L[p] = clip((inp - S + g*R)/(g+1)); S = (inp - L)/(b+1); R = (1/Kc) * sum_{256 slices} Rpart
__global__ __launch_bounds__(256) void k_reduce_LS(const float* __restrict__ Rpart,
                                                   const float* __restrict__ inp,
                                                   const float* __restrict__ pg, const float* __restrict__ pb,
                                                   float* __restrict__ S, float* __restrict__ Ldst){
  __shared__ float red[8][32];
  int tid = threadIdx.x;
  int pi = tid & 31, sg = tid >> 5;
  int p = blockIdx.x * 32 + pi;
  float acc = 0.0f;
  #pragma unroll 4
  for (int s = sg * 32; s < sg * 32 + 32; s++) acc += Rpart[(size_t)s * 8192 + p];
  red[sg][pi] = acc;
  __syncthreads();
  if (tid < 32){
    float a = 0.0f;
    #pragma unroll
    for (int q = 0; q < 8; q++) a += red[q][pi];
    float R = a * (1.0f / 2592.0f);
    float g = pg[0], b = pb[0];
    float Ln = (inp[p] - S[p] + g * R) / (g + 1.0f);
    Ln = fminf(fmaxf(Ln, 0.0f), 1.0f);
    S[p] = (inp[p] - Ln) / (b + 1.0f);
    Ldst[p] = Ln;
  }
}

// raw gram: out[r1][r2] = dot(rows[r1], rows[r2]) over len4 float4s (row stride in floats)
__global__ __launch_bounds__(64) void k_gram(const float* __restrict__ rows, int stride, int len4,
                                             float* __restrict__ out){
  int e = blockIdx.x; int r1 = e >> 6, r2 = e & 63;
  if (r2 < r1) return;
  int lane = threadIdx.x;
  const float4* a = (const float4*)(rows + (size_t)r1 * stride);
  const float4* b = (const float4*)(rows + (size_t)r2 * stride);
  float acc = 0.0f;
  for (int p = lane; p < len4; p += 64){
    float4 x = a[p], y = b[p];
    acc = fmaf(x.x, y.x, acc); acc = fmaf(x.y, y.y, acc);
    acc = fmaf(x.z, y.z, acc); acc = fmaf(x.w, y.w, acc);
  }
  for (int off = 32; off; off >>= 1) acc += __shfl_down(acc, off, 64);
  if (lane == 0){ out[r1 * 64 + r2] = acc; out[r2 * 64 + r1] = acc; }
}

// Mt_new[sbase+s][p] = 2g * sum_{r<64} (sum_z T1t[r+64z][p]) * CmInv[r][sbase+s]
__global__ __launch_bounds__(256) void k_mn(const float* __restrict__ T1t, const float* __restrict__ CmInv,
                                            const float* __restrict__ pg, float* __restrict__ Mt){
  __shared__ float4 ci4[1024];
  int tid = threadIdx.x;
  const float4* g4 = (const float4*)CmInv;
  for (int t = tid; t < 1024; t += 256) ci4[t] = g4[t];
  __syncthreads();
  int p = blockIdx.x * 256 + tid;
  int sbase = blockIdx.y * 32;
  float g2 = 2.0f * pg[0];
  float acc[32];
  #pragma unroll
  for (int s = 0; s < 32; s++) acc[s] = 0.0f;
  for (int r = 0; r < 64; r++){
    float v = T1t[(size_t)r * 8192 + p] + T1t[(size_t)(r + 64) * 8192 + p]
            + T1t[(size_t)(r + 128) * 8192 + p] + T1t[(size_t)(r + 192) * 8192 + p];
    #pragma unroll
    for (int k = 0; k < 8; k++){
      float4 c = ci4[r * 16 + (sbase >> 2) + k];
      acc[4*k+0] = fmaf(v, c.x, acc[4*k+0]);
      acc[4*k+1] = fmaf(v, c.y, acc[4*k+1]);
      acc[4*k+2] = fmaf(v, c.z, acc[4*k+2]);
      acc[4*k+3] = fmaf(v, c.w, acc[4*k+3]);
    }
  }
  #pragma unroll
  for (int s = 0; s < 32; s++) Mt[(size_t)(sbase + s) * 8192 + p] = g2 * acc[s];
}

// T2part[hc][r][col] (+ fused inv(Cn) as sentinel y==8)
__global__ __launch_bounds__(256) void k_conv_T2(const float* __restrict__ Lg,
                                                 const float* __restrict__ Mtg,
                                                 float* __restrict__ T2part,
                                                 const float* __restrict__ Gr,
                                                 const float* __restrict__ pg,
                                                 const float* __restrict__ pa,
                                                 float* __restrict__ CnI){
  __shared__ float Mi[128 * 68];
  __shared__ float4 Ls4[256];
  if (blockIdx.y == 8){
    if (blockIdx.x == 0 && threadIdx.x < 64)
      inv64(Gr, pg, pa, CnI, threadIdx.x);
    return;
  }
  int r = blockIdx.x, hc = blockIdx.y, tid = threadIdx.x;
  const float4* gm4 = (const float4*)(Mtg + (size_t)r * 8192);
  for (int t = tid; t < 2048; t += 256){
    float4 v4 = gm4[t];
    int row = t >> 4, cb = (t & 15) * 4;
    float* d = &Mi[row * 68 + cb];
    d[0] = v4.x; d[1] = v4.y; d[2] = v4.z; d[3] = v4.w;
  }
  const float4* gl4 = (const float4*)Lg;
  if (tid < 256){
    int c = tid >> 7, rem = tid & 127;
    Ls4[tid] = gl4[c * 1024 + hc * 128 + rem];
  }
  __syncthreads();
  if (tid >= 216) return;
  int kk = tid / 108, rest = tid % 108, ii = rest / 3, jj0 = (rest % 3) * 12;
  float acc[12];
  #pragma unroll
  for (int u = 0; u < 12; u++) acc[u] = 0.0f;
  #pragma unroll 1
  for (int c = 0; c < 2; c++){
    #pragma unroll 1
    for (int hl = 0; hl < 8; hl++){
      int h = hc * 8 + hl;
      const float* ib = &Mi[(((c + kk) & 1) * 64 + ((h + ii) & 63)) * 68];
      const float4* lrow = &Ls4[c * 128 + hl * 16];
      float v[16];
      {
        float4 t0 = *(const float4*)&ib[jj0];
        float4 t1 = *(const float4*)&ib[jj0 + 4];
        float4 t2 = *(const float4*)&ib[jj0 + 8];
        float4 t3 = *(const float4*)&ib[jj0 + 12];
        v[0]=t0.x; v[1]=t0.y; v[2]=t0.z; v[3]=t0.w;
        v[4]=t1.x; v[5]=t1.y; v[6]=t1.z; v[7]=t1.w;
        v[8]=t2.x; v[9]=t2.y; v[10]=t2.z; v[11]=t2.w;
        v[12]=t3.x; v[13]=t3.y; v[14]=t3.z; v[15]=t3.w;
      }
      #pragma unroll
      for (int wg = 0; wg < 16; wg++){
        float4 lv = lrow[wg];
        #pragma unroll
        for (int u = 0; u < 12; u++) acc[u] = fmaf(lv.x, v[(4*wg + 0 + u) & 15], acc[u]);
        #pragma unroll
        for (int u = 0; u < 12; u++) acc[u] = fmaf(lv.y, v[(4*wg + 1 + u) & 15], acc[u]);
        #pragma unroll
        for (int u = 0; u < 12; u++) acc[u] = fmaf(lv.z, v[(4*wg + 2 + u) & 15], acc[u]);
        #pragma unroll
        for (int u = 0; u < 12; u++) acc[u] = fmaf(lv.w, v[(4*wg + 3 + u) & 15], acc[u]);
        if (wg < 15){
          float4 nv = *(const float4*)&ib[(jj0 + 4*wg + 16) & 63];
          int s = (4*wg) & 15;
          v[s] = nv.x; v[s+1] = nv.y; v[s+2] = nv.z; v[s+3] = nv.w;
        }
      }
    }
  }
  #pragma unroll
  for (int u = 0; u < 12; u++){
    int col = kk * 1296 + (jj0 + u) * 36 + ii;
    T2part[((size_t)hc * 64 + r) * KC + col] = acc[u];
  }
}

// T2sum[t] = sum_hc T2part[hc*165888 + t]   (t = r*KC+col)
__global__ __launch_bounds__(256) void k_t2sum(const float* __restrict__ T2part, float* __restrict__ T2sum){
  int t = blockIdx.x * 256 + threadIdx.x;
  float s = 0.0f;
  #pragma unroll
  for (int hc = 0; hc < 8; hc++) s += T2part[(size_t)hc * 165888 + t];
  T2sum[t] = s;
}

// NtT[rr][d(col)] = 2g * sum_s CnInv[s][rr] * T2sum[s][col], rr in 16-chunk per blockIdx.y
__global__ __launch_bounds__(256) void k_nn(const float* __restrict__ T2sum, const float* __restrict__ CnInv,
                                            const float* __restrict__ pg,
                                            float* __restrict__ NtT){
  __shared__ float4 ci4[1024];
  int tid = threadIdx.x;
  const float4* g4 = (const float4*)CnInv;
  for (int t = tid; t < 1024; t += 256) ci4[t] = g4[t];
  __syncthreads();
  int col = blockIdx.x * 256 + tid;
  if (col >= KC) return;
  int rb = blockIdx.y * 16;
  float g2 = 2.0f * pg[0];
  float acc[16];
  #pragma unroll
  for (int rr = 0; rr < 16; rr++) acc[rr] = 0.0f;
  for (int s = 0; s < 64; s++){
    float tv = T2sum[(size_t)s * KC + col];
    #pragma unroll
    for (int k = 0; k < 4; k++){
      float4 c = ci4[s * 16 + (rb >> 2) + k];
      acc[4*k+0] = fmaf(tv, c.x, acc[4*k+0]);
      acc[4*k+1] = fmaf(tv, c.y, acc[4*k+1]);
      acc[4*k+2] = fmaf(tv, c.z, acc[4*k+2]);
      acc[4*k+3] = fmaf(tv, c.w, acc[4*k+3]);
    }
  }
  int kk = col / 1296, rest = col % 1296, jj = rest / 36, iv = rest % 36;
  int d = (kk * 36 + iv) * 36 + jj;
  #pragma unroll
  for (int rr = 0; rr < 16; rr++){
    NtT[(size_t)(rb + rr) * KCP + d] = g2 * acc[rr];
  }
}

extern "C" void kernel_launch(void* const* d_in, const int* in_sizes, int n_in,
                              void* d_out, int out_size, void* d_ws, size_t ws_size,
                              hipStream_t stream) {
  const float* inp = (const float*)d_in[0];
  const float* s0  = (const float*)d_in[1];
  const float* pa  = (const float*)d_in[2];
  const float* pb  = (const float*)d_in[3];
  const float* pg  = (const float*)d_in[4];
  float* ws  = (float*)d_ws;
  float* L   = ws + OFF_L;   float* S   = ws + OFF_S;    float* Mt  = ws + OFF_MT;
  float* NtT = ws + OFF_NTT; float* Big = ws + OFF_BIG;
  float* T2p = ws + OFF_BIG;              // aliased into Big (disjoint lifetimes)
  float* T2s = ws + OFF_BIG + 1327104u;   // aliased into Big
  float* Gr  = ws + OFF_GRAM;
  float* CmI = ws + OFF_CMI; float* CnI = ws + OFF_CNI;
  float* out = (float*)d_out;

  k_init<<<2048, 256, 0, stream>>>(inp, s0, L, S, Mt, NtT);
  for (int step = 0; step < 5; step++){
    k_conv_R<<<dim3(64, 4, 4), 128, 0, stream>>>(Mt, NtT, Big);
    bool last = (step == 4);
    k_reduce_LS<<<256, 256, 0, stream>>>(Big, inp, pg, pb, S, last ? out : L);
    if (last) break;
    k_gram<<<4096, 64, 0, stream>>>(NtT, KCP, KCP / 4, Gr);   // Cm raw = N@N^T (pad zeros)
    // conv_T1 grid z==4 carries the fused inv(Cm) sentinel workgroup
    k_conv_T1<<<dim3(64, 4, 5), 128, 0, stream>>>(L, NtT, Big, Gr, pg, pa, CmI);
    k_mn<<<dim3(32, 2), 256, 0, stream>>>(Big, CmI, pg, Mt);
    k_gram<<<4096, 64, 0, stream>>>(Mt, 8192, 2048, Gr);      // Cn raw = Mn^T@Mn
    // conv_T2 grid y==8 carries the fused inv(Cn) sentinel workgroup
    k_conv_T2<<<dim3(64, 9), 256, 0, stream>>>(L, Mt, T2p, Gr, pg, pa, CnI);
    k_t2sum<<<648, 256, 0, stream>>>(T2p, T2s);
    k_nn<<<dim3(11, 4), 256, 0, stream>>>(T2s, CnI, pg, NtT);
  }
}

// Round 9
// 939.612 us; speedup vs baseline: 2.7641x; 1.0511x over previous
//
#include <hip/hip_runtime.h>

// Problem constants: B=1, C=2, H=W=64, m=8192, mk=64, K1=K2=36, K3=2, Kc=2592, iters=6 (5 steps).
#define KC 2592
#define KCP 2624           // padded NtT row stride (zeros in tail)
#define HW 4096

// workspace layout (float offsets), total 2818048 floats = 11.27 MB (<= proven 11.29 MB)
#define OFF_L    0u
#define OFF_S    8192u
#define OFF_MT   16384u    // Mt[64][8192]
#define OFF_NTT  540672u   // NtT[64][2624], layout d=(kk*36+ii)*36+jj, cols 2592..2623 zero
#define OFF_BIG  708608u   // Rpart[256][8192] / T1t[256][8192] / (T2part[8][64][2592] + T2sum[64][2592])
#define OFF_GRAM 2805760u  // raw gram 64x64 (shared by Cm and Cn phases)
#define OFF_CMI  2809856u
#define OFF_CNI  2813952u

__global__ __launch_bounds__(256) void k_init(const float* __restrict__ inp, const float* __restrict__ s0,
                                              float* __restrict__ L, float* __restrict__ S,
                                              float* __restrict__ Mt, float* __restrict__ NtT){
  int t = blockIdx.x * 256 + threadIdx.x;
  if (t < 8192){ L[t] = inp[t]; S[t] = s0[t]; }
  if (t < 524288){ int r = t >> 13; int p = t & 8191; Mt[t] = (p == r) ? 1.0f : 0.0f; }
  if (t < 167936){ int r = t / KCP; int d = t - r * KCP;
                   int dr = (r % 36) * 36 + r / 36;   // N0: d=(0*36+ii)*36+jj with col=jj*36+ii=r
                   NtT[t] = (d == dr) ? 1.0f : 0.0f; }
}

// ---- in-register Jordan-exchange inverse of (2g*gram + a*I), SPD, no pivoting.
// Lane c holds column c in b[0..63] (template-constant indices -> VGPR-resident, R6-verified).
// Cross-lane via v_readlane BATCHED in groups of 16: R7 showed per-op readlane->SGPR->fma
// pairs cost ~12 cyc/instr in wait-states (inv wave 74 us, outliving its host conv). Grouping
// pays the SGPR hazard once per 16 ops -> ~420 cyc/pivot, ~27k cyc total (~11 us, hidden).
__device__ __forceinline__ float readlane_f(float x, int lane){
  return __uint_as_float(__builtin_amdgcn_readlane(__float_as_uint(x), lane));
}
template<int K>
__device__ __forceinline__ void gj_step(float (&b)[64], int lane){
  float bk = b[K];
  float akk = readlane_f(bk, K);         // A[K][K], uniform (SGPR)
  float p = 1.0f / akk;
  bool isk = (lane == K);
  float t = isk ? 1.0f : bk;             // A[K][c] operand (lane K: virtual 1 on diag)
  float pt = p * t;
  #pragma unroll
  for (int g = 0; g < 4; g++){           // 16-wide batches: readlanes first, then fmas
    float f[16];
    #pragma unroll
    for (int u = 0; u < 16; u++){
      int i = g * 16 + u;
      if (i == K) continue;
      f[u] = readlane_f(b[i], K);        // A[i][K], uniform -> SGPR (batched)
    }
    #pragma unroll
    for (int u = 0; u < 16; u++){
      int i = g * 16 + u;
      if (i == K) continue;
      float base = isk ? 0.0f : b[i];
      b[i] = fmaf(-f[u], pt, base);      // lane K: column K = -f*p; else A[i][c] -= f*pt
    }
  }
  b[K] = t * p;                          // lane K: p; else row K scaled
}
template<int K> struct GJ {
  static __device__ __forceinline__ void run(float (&b)[64], int lane){
    gj_step<K>(b, lane);
    GJ<K + 1>::run(b, lane);
  }
};
template<> struct GJ<64> {
  static __device__ __forceinline__ void run(float (&b)[64], int lane){}
};
__device__ void inv64(const float* __restrict__ src, const float* __restrict__ pg,
                      const float* __restrict__ pa, float* __restrict__ dst, int lane){
  float scale = 2.0f * pg[0];
  float ad = pa[0];
  float b[64];
  #pragma unroll
  for (int i = 0; i < 64; i++)
    b[i] = scale * src[i * 64 + lane] + ((i == lane) ? ad : 0.0f);
  GJ<0>::run(b, lane);
  #pragma unroll
  for (int i = 0; i < 64; i++)
    dst[i * 64 + lane] = b[i];
}

// ---- conv_R: Rpart[r+64z][p] = sum_{kk, ii in 9-quarter z, jj} Mt[r][(c+kk)%2][(h+ii)%64][(w+jj)%64] * f[kk][ii][jj]
// 128 thr = 2c x 16h x 4wq; 16 outputs/thread; LDS holds only the 24 needed rows per c.
__global__ __launch_bounds__(128) void k_conv_R(const float* __restrict__ Mtg,
                                                const float* __restrict__ NtT,
                                                float* __restrict__ Rpart){
  __shared__ float img[2][24][68];
  __shared__ float4 filt4[162];
  int r = blockIdx.x, oct = blockIdx.y, z = blockIdx.z, tid = threadIdx.x;
  int rowbase = oct * 16 + z * 9;
  const float4* gi4 = (const float4*)(Mtg + (size_t)r * 8192);
  for (int t = tid; t < 768; t += 128){
    int fw = t & 15, rr = t >> 4;
    int c = (rr >= 24) ? 1 : 0, q = rr - c * 24;
    int gr = (rowbase + q) & 63;
    float4 v4 = gi4[(c * 64 + gr) * 16 + fw];
    float* d = &img[c][q][fw * 4];
    d[0] = v4.x; d[1] = v4.y; d[2] = v4.z; d[3] = v4.w;
  }
  int iilo = z * 9;
  const float* gf = NtT + (size_t)r * KCP;
  for (int t = tid; t < 162; t += 128){
    int kk = t / 81; int rem4 = t - kk * 81;
    filt4[t] = *(const float4*)(gf + kk * 1296 + iilo * 36 + rem4 * 4);
  }
  __syncthreads();
  int c0 = tid >> 6, hl = (tid >> 2) & 15, w0 = (tid & 3) * 16;
  float acc[16];
  #pragma unroll
  for (int u = 0; u < 16; u++) acc[u] = 0.0f;
  #pragma unroll 1
  for (int kk = 0; kk < 2; kk++){
    int cimg = (c0 + kk) & 1;
    #pragma unroll 1
    for (int iix = 0; iix < 9; iix++){
      const float* ib = img[cimg][hl + iix];
      float v[32];
      #pragma unroll
      for (int t = 0; t < 8; t++){
        float4 t4 = *(const float4*)&ib[(w0 + 4 * t) & 63];
        v[4*t] = t4.x; v[4*t+1] = t4.y; v[4*t+2] = t4.z; v[4*t+3] = t4.w;
      }
      const float4* fb = &filt4[kk * 81 + iix * 9];
      #pragma unroll
      for (int g = 0; g < 9; g++){
        float4 ff = fb[g];
        #pragma unroll
        for (int u = 0; u < 16; u++) acc[u] = fmaf(ff.x, v[(4*g + 0 + u) & 31], acc[u]);
        #pragma unroll
        for (int u = 0; u < 16; u++) acc[u] = fmaf(ff.y, v[(4*g + 1 + u) & 31], acc[u]);
        #pragma unroll
        for (int u = 0; u < 16; u++) acc[u] = fmaf(ff.z, v[(4*g + 2 + u) & 31], acc[u]);
        #pragma unroll
        for (int u = 0; u < 16; u++) acc[u] = fmaf(ff.w, v[(4*g + 3 + u) & 31], acc[u]);
        if (g < 5){
          float4 nv = *(const float4*)&ib[(w0 + 32 + 4*g) & 63];
          int s = (4*g) & 31;
          v[s] = nv.x; v[s+1] = nv.y; v[s+2] = nv.z; v[s+3] = nv.w;
        }
      }
    }
  }
  int h = oct * 16 + hl;
  size_t ob = ((size_t)r + 64 * z) * 8192 + (size_t)(c0 * HW + h * 64 + w0);
  *(float4*)&Rpart[ob]      = make_float4(acc[0], acc[1], acc[2], acc[3]);
  *(float4*)&Rpart[ob + 4]  = make_float4(acc[4], acc[5], acc[6], acc[7]);
  *(float4*)&Rpart[ob + 8]  = make_float4(acc[8], acc[9], acc[10], acc[11]);
  *(float4*)&Rpart[ob + 12] = make_float4(acc[12], acc[13], acc[14], acc[15]);
}

// ---- conv_T1 (+ fused inv(Cm) as sentinel z==4): T1t[r+64z][p] = sum L[...] * f[kk][ii][jj]
__global__ __launch_bounds__(128) void k_conv_T1(const float* __restrict__ Lg,
                                                 const float* __restrict__ NtT,
                                                 float* __restrict__ T1t,
                                                 const float* __restrict__ Gr,
                                                 const float* __restrict__ pg,
                                                 const float* __restrict__ pa,
                                                 float* __restrict__ CmI){
  __shared__ float img[2][24][68];
  __shared__ float4 filt4[162];
  if (blockIdx.z == 4){
    if (blockIdx.x == 0 && blockIdx.y == 0 && threadIdx.x < 64)
      inv64(Gr, pg, pa, CmI, threadIdx.x);
    return;
  }
  int r = blockIdx.x, oct = blockIdx.y, z = blockIdx.z, tid = threadIdx.x;
  int rowbase = (oct * 16 - z * 9 - 8 + 128) & 63;     // stored q <-> global row (rowbase+q)&63
  const float4* gi4 = (const float4*)Lg;
  for (int t = tid; t < 768; t += 128){
    int fw = t & 15, rr = t >> 4;
    int c = (rr >= 24) ? 1 : 0, q = rr - c * 24;
    int gr = (rowbase + q) & 63;
    float4 v4 = gi4[(c * 64 + gr) * 16 + fw];
    float* d = &img[c][q][fw * 4];
    d[0] = v4.x; d[1] = v4.y; d[2] = v4.z; d[3] = v4.w;
  }
  int iilo = z * 9;
  const float* gf = NtT + (size_t)r * KCP;
  for (int t = tid; t < 162; t += 128){
    int kk = t / 81; int rem4 = t - kk * 81;
    filt4[t] = *(const float4*)(gf + kk * 1296 + iilo * 36 + rem4 * 4);
  }
  __syncthreads();
  int c0 = tid >> 6, hl = (tid >> 2) & 15, w0 = (tid & 3) * 16;
  float acc[16];
  #pragma unroll
  for (int u = 0; u < 16; u++) acc[u] = 0.0f;
  #pragma unroll 1
  for (int kk = 0; kk < 2; kk++){
    int cimg = (c0 - kk + 2) & 1;
    #pragma unroll 1
    for (int iix = 0; iix < 9; iix++){
      const float* ib = img[cimg][hl - iix + 8];       // (h-ii) row
      float v[32];                                     // v[(rel)&31] holds img[w0+rel]
      {
        float4 tm = *(const float4*)&ib[(w0 - 4 + 64) & 63];   // rel -4..-1 -> slots 28..31
        v[28] = tm.x; v[29] = tm.y; v[30] = tm.z; v[31] = tm.w;
      }
      #pragma unroll
      for (int t = 0; t < 4; t++){
        float4 t4 = *(const float4*)&ib[(w0 + 4 * t) & 63];    // rel 0..15
        v[4*t] = t4.x; v[4*t+1] = t4.y; v[4*t+2] = t4.z; v[4*t+3] = t4.w;
      }
      const float4* fb = &filt4[kk * 81 + iix * 9];
      #pragma unroll
      for (int g = 0; g < 9; g++){
        float4 ff = fb[g];
        #pragma unroll
        for (int u = 0; u < 16; u++) acc[u] = fmaf(ff.x, v[(u - (4*g + 0)) & 31], acc[u]);
        #pragma unroll
        for (int u = 0; u < 16; u++) acc[u] = fmaf(ff.y, v[(u - (4*g + 1)) & 31], acc[u]);
        #pragma unroll
        for (int u = 0; u < 16; u++) acc[u] = fmaf(ff.z, v[(u - (4*g + 2)) & 31], acc[u]);
        #pragma unroll
        for (int u = 0; u < 16; u++) acc[u] = fmaf(ff.w, v[(u - (4*g + 3)) & 31], acc[u]);
        if (g < 8){
          float4 nv = *(const float4*)&ib[(w0 - 8 - 4*g + 128) & 63];  // rel -8-4g..-5-4g
          int s = (-8 - 4*g) & 31;
          v[s] = nv.x; v[s+1] = nv.y; v[s+2] = nv.z; v[s+3] = nv.w;
        }
      }
    }
  }
  int h = oct * 16 + hl;
  size_t ob = ((size_t)r + 64 * z) * 8192 + (size_t)(c0 * HW + h * 64 + w0);
  *(float4*)&T1t[ob]      = make_float4(acc[0], acc[1], acc[2], acc[3]);
  *(float4*)&T1t[ob + 4]  = make_float4(acc[4], acc[5], acc[6], acc[7]);
  *(float4*)&T1t[ob + 8]  = make_float4(acc[8], acc[9], acc[10], acc[11]);
  *(float4*)&T1t[ob + 12] = make_float4(acc[12], acc[13], acc[14], acc[15]);
}

// L[p] = clip((inp - S + g*R)/(g+1)); S = (inp - L)/(b+1); R = (1/Kc) * sum_{256 slices} Rpart
__global__ __launch_bounds__(256) void k_reduce_LS(const float* __restrict__ Rpart,
                                                   const float* __restrict__ inp,
                                                   const float* __restrict__ pg, const float* __restrict__ pb,
                                                   float* __restrict__ S, float* __restrict__ Ldst){
  __shared__ float red[8][32];
  int tid = threadIdx.x;
  int pi = tid & 31, sg = tid >> 5;
  int p = blockIdx.x * 32 + pi;
  float acc = 0.0f;
  #pragma unroll 4
  for (int s = sg * 32; s < sg * 32 + 32; s++) acc += Rpart[(size_t)s * 8192 + p];
  red[sg][pi] = acc;
  __syncthreads();
  if (tid < 32){
    float a = 0.0f;
    #pragma unroll
    for (int q = 0; q < 8; q++) a += red[q][pi];
    float R = a * (1.0f / 2592.0f);
    float g = pg[0], b = pb[0];
    float Ln = (inp[p] - S[p] + g * R) / (g + 1.0f);
    Ln = fminf(fmaxf(Ln, 0.0f), 1.0f);
    S[p] = (inp[p] - Ln) / (b + 1.0f);
    Ldst[p] = Ln;
  }
}

// raw gram: out[r1][r2] = dot(rows[r1], rows[r2]) over len4 float4s (row stride in floats)
__global__ __launch_bounds__(64) void k_gram(const float* __restrict__ rows, int stride, int len4,
                                             float* __restrict__ out){
  int e = blockIdx.x; int r1 = e >> 6, r2 = e & 63;
  if (r2 < r1) return;
  int lane = threadIdx.x;
  const float4* a = (const float4*)(rows + (size_t)r1 * stride);
  const float4* b = (const float4*)(rows + (size_t)r2 * stride);
  float acc = 0.0f;
  for (int p = lane; p < len4; p += 64){
    float4 x = a[p], y = b[p];
    acc = fmaf(x.x, y.x, acc); acc = fmaf(x.y, y.y, acc);
    acc = fmaf(x.z, y.z, acc); acc = fmaf(x.w, y.w, acc);
  }
  for (int off = 32; off; off >>= 1) acc += __shfl_down(acc, off, 64);
  if (lane == 0){ out[r1 * 64 + r2] = acc; out[r2 * 64 + r1] = acc; }
}

// Mt_new[sbase+s][p] = 2g * sum_{r<64} (sum_z T1t[r+64z][p]) * CmInv[r][sbase+s]
__global__ __launch_bounds__(256) void k_mn(const float* __restrict__ T1t, const float* __restrict__ CmInv,
                                            const float* __restrict__ pg, float* __restrict__ Mt){
  __shared__ float4 ci4[1024];
  int tid = threadIdx.x;
  const float4* g4 = (const float4*)CmInv;
  for (int t = tid; t < 1024; t += 256) ci4[t] = g4[t];
  __syncthreads();
  int p = blockIdx.x * 256 + tid;
  int sbase = blockIdx.y * 32;
  float g2 = 2.0f * pg[0];
  float acc[32];
  #pragma unroll
  for (int s = 0; s < 32; s++) acc[s] = 0.0f;
  for (int r = 0; r < 64; r++){
    float v = T1t[(size_t)r * 8192 + p] + T1t[(size_t)(r + 64) * 8192 + p]
            + T1t[(size_t)(r + 128) * 8192 + p] + T1t[(size_t)(r + 192) * 8192 + p];
    #pragma unroll
    for (int k = 0; k < 8; k++){
      float4 c = ci4[r * 16 + (sbase >> 2) + k];
      acc[4*k+0] = fmaf(v, c.x, acc[4*k+0]);
      acc[4*k+1] = fmaf(v, c.y, acc[4*k+1]);
      acc[4*k+2] = fmaf(v, c.z, acc[4*k+2]);
      acc[4*k+3] = fmaf(v, c.w, acc[4*k+3]);
    }
  }
  #pragma unroll
  for (int s = 0; s < 32; s++) Mt[(size_t)(sbase + s) * 8192 + p] = g2 * acc[s];
}

// T2part[hc][r][col] (+ fused inv(Cn) as sentinel y==8)
__global__ __launch_bounds__(256) void k_conv_T2(const float* __restrict__ Lg,
                                                 const float* __restrict__ Mtg,
                                                 float* __restrict__ T2part,
                                                 const float* __restrict__ Gr,
                                                 const float* __restrict__ pg,
                                                 const float* __restrict__ pa,
                                                 float* __restrict__ CnI){
  __shared__ float Mi[128 * 68];
  __shared__ float4 Ls4[256];
  if (blockIdx.y == 8){
    if (blockIdx.x == 0 && threadIdx.x < 64)
      inv64(Gr, pg, pa, CnI, threadIdx.x);
    return;
  }
  int r = blockIdx.x, hc = blockIdx.y, tid = threadIdx.x;
  const float4* gm4 = (const float4*)(Mtg + (size_t)r * 8192);
  for (int t = tid; t < 2048; t += 256){
    float4 v4 = gm4[t];
    int row = t >> 4, cb = (t & 15) * 4;
    float* d = &Mi[row * 68 + cb];
    d[0] = v4.x; d[1] = v4.y; d[2] = v4.z; d[3] = v4.w;
  }
  const float4* gl4 = (const float4*)Lg;
  if (tid < 256){
    int c = tid >> 7, rem = tid & 127;
    Ls4[tid] = gl4[c * 1024 + hc * 128 + rem];
  }
  __syncthreads();
  if (tid >= 216) return;
  int kk = tid / 108, rest = tid % 108, ii = rest / 3, jj0 = (rest % 3) * 12;
  float acc[12];
  #pragma unroll
  for (int u = 0; u < 12; u++) acc[u] = 0.0f;
  #pragma unroll 1
  for (int c = 0; c < 2; c++){
    #pragma unroll 1
    for (int hl = 0; hl < 8; hl++){
      int h = hc * 8 + hl;
      const float* ib = &Mi[(((c + kk) & 1) * 64 + ((h + ii) & 63)) * 68];
      const float4* lrow = &Ls4[c * 128 + hl * 16];
      float v[16];
      {
        float4 t0 = *(const float4*)&ib[jj0];
        float4 t1 = *(const float4*)&ib[jj0 + 4];
        float4 t2 = *(const float4*)&ib[jj0 + 8];
        float4 t3 = *(const float4*)&ib[jj0 + 12];
        v[0]=t0.x; v[1]=t0.y; v[2]=t0.z; v[3]=t0.w;
        v[4]=t1.x; v[5]=t1.y; v[6]=t1.z; v[7]=t1.w;
        v[8]=t2.x; v[9]=t2.y; v[10]=t2.z; v[11]=t2.w;
        v[12]=t3.x; v[13]=t3.y; v[14]=t3.z; v[15]=t3.w;
      }
      #pragma unroll
      for (int wg = 0; wg < 16; wg++){
        float4 lv = lrow[wg];
        #pragma unroll
        for (int u = 0; u < 12; u++) acc[u] = fmaf(lv.x, v[(4*wg + 0 + u) & 15], acc[u]);
        #pragma unroll
        for (int u = 0; u < 12; u++) acc[u] = fmaf(lv.y, v[(4*wg + 1 + u) & 15], acc[u]);
        #pragma unroll
        for (int u = 0; u < 12; u++) acc[u] = fmaf(lv.z, v[(4*wg + 2 + u) & 15], acc[u]);
        #pragma unroll
        for (int u = 0; u < 12; u++) acc[u] = fmaf(lv.w, v[(4*wg + 3 + u) & 15], acc[u]);
        if (wg < 15){
          float4 nv = *(const float4*)&ib[(jj0 + 4*wg + 16) & 63];
          int s = (4*wg) & 15;
          v[s] = nv.x; v[s+1] = nv.y; v[s+2] = nv.z; v[s+3] = nv.w;
        }
      }
    }
  }
  #pragma unroll
  for (int u = 0; u < 12; u++){
    int col = kk * 1296 + (jj0 + u) * 36 + ii;
    T2part[((size_t)hc * 64 + r) * KC + col] = acc[u];
  }
}

// T2sum[t] = sum_hc T2part[hc*165888 + t]   (t = r*KC+col)
__global__ __launch_bounds__(256) void k_t2sum(const float* __restrict__ T2part, float* __restrict__ T2sum){
  int t = blockIdx.x * 256 + threadIdx.x;
  float s = 0.0f;
  #pragma unroll
  for (int hc = 0; hc < 8; hc++) s += T2part[(size_t)hc * 165888 + t];
  T2sum[t] = s;
}

// NtT[rr][d(col)] = 2g * sum_s CnInv[s][rr] * T2sum[s][col], rr in 16-chunk per blockIdx.y
__global__ __launch_bounds__(256) void k_nn(const float* __restrict__ T2sum, const float* __restrict__ CnInv,
                                            const float* __restrict__ pg,
                                            float* __restrict__ NtT){
  __shared__ float4 ci4[1024];
  int tid = threadIdx.x;
  const float4* g4 = (const float4*)CnInv;
  for (int t = tid; t < 1024; t += 256) ci4[t] = g4[t];
  __syncthreads();
  int col = blockIdx.x * 256 + tid;
  if (col >= KC) return;
  int rb = blockIdx.y * 16;
  float g2 = 2.0f * pg[0];
  float acc[16];
  #pragma unroll
  for (int rr = 0; rr < 16; rr++) acc[rr] = 0.0f;
  for (int s = 0; s < 64; s++){
    float tv = T2sum[(size_t)s * KC + col];
    #pragma unroll
    for (int k = 0; k < 4; k++){
      float4 c = ci4[s * 16 + (rb >> 2) + k];
      acc[4*k+0] = fmaf(tv, c.x, acc[4*k+0]);
      acc[4*k+1] = fmaf(tv, c.y, acc[4*k+1]);
      acc[4*k+2] = fmaf(tv, c.z, acc[4*k+2]);
      acc[4*k+3] = fmaf(tv, c.w, acc[4*k+3]);
    }
  }
  int kk = col / 1296, rest = col % 1296, jj = rest / 36, iv = rest % 36;
  int d = (kk * 36 + iv) * 36 + jj;
  #pragma unroll
  for (int rr = 0; rr < 16; rr++){
    NtT[(size_t)(rb + rr) * KCP + d] = g2 * acc[rr];
  }
}

extern "C" void kernel_launch(void* const* d_in, const int* in_sizes, int n_in,
                              void* d_out, int out_size, void* d_ws, size_t ws_size,
                              hipStream_t stream) {
  const float* inp = (const float*)d_in[0];
  const float* s0  = (const float*)d_in[1];
  const float* pa  = (const float*)d_in[2];
  const float* pb  = (const float*)d_in[3];
  const float* pg  = (const float*)d_in[4];
  float* ws  = (float*)d_ws;
  float* L   = ws + OFF_L;   float* S   = ws + OFF_S;    float* Mt  = ws + OFF_MT;
  float* NtT = ws + OFF_NTT; float* Big = ws + OFF_BIG;
  float* T2p = ws + OFF_BIG;              // aliased into Big (disjoint lifetimes)
  float* T2s = ws + OFF_BIG + 1327104u;   // aliased into Big
  float* Gr  = ws + OFF_GRAM;
  float* CmI = ws + OFF_CMI; float* CnI = ws + OFF_CNI;
  float* out = (float*)d_out;

  k_init<<<2048, 256, 0, stream>>>(inp, s0, L, S, Mt, NtT);
  for (int step = 0; step < 5; step++){
    k_conv_R<<<dim3(64, 4, 4), 128, 0, stream>>>(Mt, NtT, Big);
    bool last = (step == 4);
    k_reduce_LS<<<256, 256, 0, stream>>>(Big, inp, pg, pb, S, last ? out : L);
    if (last) break;
    k_gram<<<4096, 64, 0, stream>>>(NtT, KCP, KCP / 4, Gr);   // Cm raw = N@N^T (pad zeros)
    // conv_T1 grid z==4 carries the fused inv(Cm) sentinel workgroup
    k_conv_T1<<<dim3(64, 4, 5), 128, 0, stream>>>(L, NtT, Big, Gr, pg, pa, CmI);
    k_mn<<<dim3(32, 2), 256, 0, stream>>>(Big, CmI, pg, Mt);
    k_gram<<<4096, 64, 0, stream>>>(Mt, 8192, 2048, Gr);      // Cn raw = Mn^T@Mn
    // conv_T2 grid y==8 carries the fused inv(Cn) sentinel workgroup
    k_conv_T2<<<dim3(64, 9), 256, 0, stream>>>(L, Mt, T2p, Gr, pg, pa, CnI);
    k_t2sum<<<648, 256, 0, stream>>>(T2p, T2s);
    k_nn<<<dim3(11, 4), 256, 0, stream>>>(T2s, CnI, pg, NtT);
  }
}

// Round 10
// 906.431 us; speedup vs baseline: 2.8653x; 1.0366x over previous
//
#include <hip/hip_runtime.h>

// Problem constants: B=1, C=2, H=W=64, m=8192, mk=64, K1=K2=36, K3=2, Kc=2592, iters=6 (5 steps).
#define KC 2592
#define KCP 2624           // padded NtT row stride (zeros in tail)
#define HW 4096

// workspace layout (float offsets), total 2822144 floats = 11.29 MB (== R1 proven footprint)
#define OFF_L    0u
#define OFF_S    8192u
#define OFF_MT   16384u    // Mt[64][8192]
#define OFF_NTT  540672u   // NtT[64][2624], layout d=(kk*36+ii)*36+jj, cols 2592..2623 zero
#define OFF_BIG  708608u   // Rpart[256][8192] / T1t[256][8192] / (T2part[8][64][2592] + T2sum[64][2592])
#define OFF_GRAM 2805760u  // raw gram 64x64 (shared by Cm and Cn phases)
#define OFF_CMI  2809856u
#define OFF_CNI  2813952u
#define OFF_ST   2818048u  // inv phase-chain state (64x64), Cm/Cn lifetimes disjoint

__global__ __launch_bounds__(256) void k_init(const float* __restrict__ inp, const float* __restrict__ s0,
                                              float* __restrict__ L, float* __restrict__ S,
                                              float* __restrict__ Mt, float* __restrict__ NtT){
  int t = blockIdx.x * 256 + threadIdx.x;
  if (t < 8192){ L[t] = inp[t]; S[t] = s0[t]; }
  if (t < 524288){ int r = t >> 13; int p = t & 8191; Mt[t] = (p == r) ? 1.0f : 0.0f; }
  if (t < 167936){ int r = t / KCP; int d = t - r * KCP;
                   int dr = (r % 36) * 36 + r / 36;   // N0: d=(0*36+ii)*36+jj with col=jj*36+ii=r
                   NtT[t] = (d == dr) ? 1.0f : 0.0f; }
}

// ---- in-register Jordan-exchange inverse of (2g*gram + a*I), SPD, no pivoting.
// Lane c holds column c in b[0..63] (template-constant indices -> VGPR-resident, R6-verified).
// R8 post-mortem: the lone sentinel wave is icache-fetch/issue bound (~40 us for ~100 KB of
// once-executed straight-line code; R6 FETCH_SIZE=127KB) — so the inv is SPLIT INTO PHASES
// hosted in consecutive kernels (state via 16 KB global buffer), each phase hidden under the
// host conv's ~25 us of real work, with conv blocks keeping clocks boosted.
__device__ __forceinline__ float readlane_f(float x, int lane){
  return __uint_as_float(__builtin_amdgcn_readlane(__float_as_uint(x), lane));
}
template<int K>
__device__ __forceinline__ void gj_step(float (&b)[64], int lane){
  float bk = b[K];
  float akk = readlane_f(bk, K);         // A[K][K], uniform (SGPR)
  float p = 1.0f / akk;
  bool isk = (lane == K);
  float t = isk ? 1.0f : bk;             // A[K][c] operand (lane K: virtual 1 on diag)
  float pt = p * t;
  #pragma unroll
  for (int g = 0; g < 4; g++){           // 16-wide batches: readlanes first, then fmas
    float f[16];
    #pragma unroll
    for (int u = 0; u < 16; u++){
      int i = g * 16 + u;
      if (i == K) continue;
      f[u] = readlane_f(b[i], K);        // A[i][K], uniform -> SGPR (batched)
    }
    #pragma unroll
    for (int u = 0; u < 16; u++){
      int i = g * 16 + u;
      if (i == K) continue;
      float base = isk ? 0.0f : b[i];
      b[i] = fmaf(-f[u], pt, base);      // lane K: column K = -f*p; else A[i][c] -= f*pt
    }
  }
  b[K] = t * p;                          // lane K: p; else row K scaled
}
template<int K0, int K1> struct GJR {
  static __device__ __forceinline__ void run(float (&b)[64], int lane){
    gj_step<K0>(b, lane);
    GJR<K0 + 1, K1>::run(b, lane);
  }
};
template<int KE> struct GJR<KE, KE> {
  static __device__ __forceinline__ void run(float (&b)[64], int lane){}
};
template<int PH>
__device__ void inv64_phaseA(const float* __restrict__ src, const float* __restrict__ pg,
                             const float* __restrict__ pa, float* __restrict__ state, int lane){
  float scale = 2.0f * pg[0];
  float ad = pa[0];
  float b[64];
  #pragma unroll
  for (int i = 0; i < 64; i++)
    b[i] = scale * src[i * 64 + lane] + ((i == lane) ? ad : 0.0f);
  GJR<0, PH>::run(b, lane);
  #pragma unroll
  for (int i = 0; i < 64; i++) state[i * 64 + lane] = b[i];
}
template<int PH>
__device__ void inv64_phaseB(const float* __restrict__ state, float* __restrict__ dst, int lane){
  float b[64];
  #pragma unroll
  for (int i = 0; i < 64; i++) b[i] = state[i * 64 + lane];
  GJR<PH, 64>::run(b, lane);
  #pragma unroll
  for (int i = 0; i < 64; i++) dst[i * 64 + lane] = b[i];
}

// ---- conv_R (+ fused inv(Cm) PHASE A as sentinel z==4):
// Rpart[r+64z][p] = sum_{kk, ii in 9-quarter z, jj} Mt[r][(c+kk)%2][(h+ii)%64][(w+jj)%64] * f[kk][ii][jj]
__global__ __launch_bounds__(128) void k_conv_R(const float* __restrict__ Mtg,
                                                const float* __restrict__ NtT,
                                                float* __restrict__ Rpart,
                                                const float* __restrict__ Gr,
                                                const float* __restrict__ pg,
                                                const float* __restrict__ pa,
                                                float* __restrict__ state){
  __shared__ float img[2][24][68];
  __shared__ float4 filt4[162];
  if (blockIdx.z == 4){
    if (blockIdx.x == 0 && blockIdx.y == 0 && threadIdx.x < 64)
      inv64_phaseA<32>(Gr, pg, pa, state, threadIdx.x);
    return;
  }
  int r = blockIdx.x, oct = blockIdx.y, z = blockIdx.z, tid = threadIdx.x;
  int rowbase = oct * 16 + z * 9;
  const float4* gi4 = (const float4*)(Mtg + (size_t)r * 8192);
  for (int t = tid; t < 768; t += 128){
    int fw = t & 15, rr = t >> 4;
    int c = (rr >= 24) ? 1 : 0, q = rr - c * 24;
    int gr = (rowbase + q) & 63;
    float4 v4 = gi4[(c * 64 + gr) * 16 + fw];
    float* d = &img[c][q][fw * 4];
    d[0] = v4.x; d[1] = v4.y; d[2] = v4.z; d[3] = v4.w;
  }
  int iilo = z * 9;
  const float* gf = NtT + (size_t)r * KCP;
  for (int t = tid; t < 162; t += 128){
    int kk = t / 81; int rem4 = t - kk * 81;
    filt4[t] = *(const float4*)(gf + kk * 1296 + iilo * 36 + rem4 * 4);
  }
  __syncthreads();
  int c0 = tid >> 6, hl = (tid >> 2) & 15, w0 = (tid & 3) * 16;
  float acc[16];
  #pragma unroll
  for (int u = 0; u < 16; u++) acc[u] = 0.0f;
  #pragma unroll 1
  for (int kk = 0; kk < 2; kk++){
    int cimg = (c0 + kk) & 1;
    #pragma unroll 1
    for (int iix = 0; iix < 9; iix++){
      const float* ib = img[cimg][hl + iix];
      float v[32];
      #pragma unroll
      for (int t = 0; t < 8; t++){
        float4 t4 = *(const float4*)&ib[(w0 + 4 * t) & 63];
        v[4*t] = t4.x; v[4*t+1] = t4.y; v[4*t+2] = t4.z; v[4*t+3] = t4.w;
      }
      const float4* fb = &filt4[kk * 81 + iix * 9];
      #pragma unroll
      for (int g = 0; g < 9; g++){
        float4 ff = fb[g];
        #pragma unroll
        for (int u = 0; u < 16; u++) acc[u] = fmaf(ff.x, v[(4*g + 0 + u) & 31], acc[u]);
        #pragma unroll
        for (int u = 0; u < 16; u++) acc[u] = fmaf(ff.y, v[(4*g + 1 + u) & 31], acc[u]);
        #pragma unroll
        for (int u = 0; u < 16; u++) acc[u] = fmaf(ff.z, v[(4*g + 2 + u) & 31], acc[u]);
        #pragma unroll
        for (int u = 0; u < 16; u++) acc[u] = fmaf(ff.w, v[(4*g + 3 + u) & 31], acc[u]);
        if (g < 5){
          float4 nv = *(const float4*)&ib[(w0 + 32 + 4*g) & 63];
          int s = (4*g) & 31;
          v[s] = nv.x; v[s+1] = nv.y; v[s+2] = nv.z; v[s+3] = nv.w;
        }
      }
    }
  }
  int h = oct * 16 + hl;
  size_t ob = ((size_t)r + 64 * z) * 8192 + (size_t)(c0 * HW + h * 64 + w0);
  *(float4*)&Rpart[ob]      = make_float4(acc[0], acc[1], acc[2], acc[3]);
  *(float4*)&Rpart[ob + 4]  = make_float4(acc[4], acc[5], acc[6], acc[7]);
  *(float4*)&Rpart[ob + 8]  = make_float4(acc[8], acc[9], acc[10], acc[11]);
  *(float4*)&Rpart[ob + 12] = make_float4(acc[12], acc[13], acc[14], acc[15]);
}

// ---- conv_T1 (+ fused inv(Cm) PHASE B as sentinel z==4): T1t[r+64z][p] = sum L[...] * f[kk][ii][jj]
__global__ __launch_bounds__(128) void k_conv_T1(const float* __restrict__ Lg,
                                                 const float* __restrict__ NtT,
                                                 float* __restrict__ T1t,
                                                 const float* __restrict__ state,
                                                 float* __restrict__ CmI){
  __shared__ float img[2][24][68];
  __shared__ float4 filt4[162];
  if (blockIdx.z == 4){
    if (blockIdx.x == 0 && blockIdx.y == 0 && threadIdx.x < 64)
      inv64_phaseB<32>(state, CmI, threadIdx.x);
    return;
  }
  int r = blockIdx.x, oct = blockIdx.y, z = blockIdx.z, tid = threadIdx.x;
  int rowbase = (oct * 16 - z * 9 - 8 + 128) & 63;     // stored q <-> global row (rowbase+q)&63
  const float4* gi4 = (const float4*)Lg;
  for (int t = tid; t < 768; t += 128){
    int fw = t & 15, rr = t >> 4;
    int c = (rr >= 24) ? 1 : 0, q = rr - c * 24;
    int gr = (rowbase + q) & 63;
    float4 v4 = gi4[(c * 64 + gr) * 16 + fw];
    float* d = &img[c][q][fw * 4];
    d[0] = v4.x; d[1] = v4.y; d[2] = v4.z; d[3] = v4.w;
  }
  int iilo = z * 9;
  const float* gf = NtT + (size_t)r * KCP;
  for (int t = tid; t < 162; t += 128){
    int kk = t / 81; int rem4 = t - kk * 81;
    filt4[t] = *(const float4*)(gf + kk * 1296 + iilo * 36 + rem4 * 4);
  }
  __syncthreads();
  int c0 = tid >> 6, hl = (tid >> 2) & 15, w0 = (tid & 3) * 16;
  float acc[16];
  #pragma unroll
  for (int u = 0; u < 16; u++) acc[u] = 0.0f;
  #pragma unroll 1
  for (int kk = 0; kk < 2; kk++){
    int cimg = (c0 - kk + 2) & 1;
    #pragma unroll 1
    for (int iix = 0; iix < 9; iix++){
      const float* ib = img[cimg][hl - iix + 8];       // (h-ii) row
      float v[32];                                     // v[(rel)&31] holds img[w0+rel]
      {
        float4 tm = *(const float4*)&ib[(w0 - 4 + 64) & 63];   // rel -4..-1 -> slots 28..31
        v[28] = tm.x; v[29] = tm.y; v[30] = tm.z; v[31] = tm.w;
      }
      #pragma unroll
      for (int t = 0; t < 4; t++){
        float4 t4 = *(const float4*)&ib[(w0 + 4 * t) & 63];    // rel 0..15
        v[4*t] = t4.x; v[4*t+1] = t4.y; v[4*t+2] = t4.z; v[4*t+3] = t4.w;
      }
      const float4* fb = &filt4[kk * 81 + iix * 9];
      #pragma unroll
      for (int g = 0; g < 9; g++){
        float4 ff = fb[g];
        #pragma unroll
        for (int u = 0; u < 16; u++) acc[u] = fmaf(ff.x, v[(u - (4*g + 0)) & 31], acc[u]);
        #pragma unroll
        for (int u = 0; u < 16; u++) acc[u] = fmaf(ff.y, v[(u - (4*g + 1)) & 31], acc[u]);
        #pragma unroll
        for (int u = 0; u < 16; u++) acc[u] = fmaf(ff.z, v[(u - (4*g + 2)) & 31], acc[u]);
        #pragma unroll
        for (int u = 0; u < 16; u++) acc[u] = fmaf(ff.w, v[(u - (4*g + 3)) & 31], acc[u]);
        if (g < 8){
          float4 nv = *(const float4*)&ib[(w0 - 8 - 4*g + 128) & 63];  // rel -8-4g..-5-4g
          int s = (-8 - 4*g) & 31;
          v[s] = nv.x; v[s+1] = nv.y; v[s+2] = nv.z; v[s+3] = nv.w;
        }
      }
    }
  }
  int h = oct * 16 + hl;
  size_t ob = ((size_t)r + 64 * z) * 8192 + (size_t)(c0 * HW + h * 64 + w0);
  *(float4*)&T1t[ob]      = make_float4(acc[0], acc[1], acc[2], acc[3]);
  *(float4*)&T1t[ob + 4]  = make_float4(acc[4], acc[5], acc[6], acc[7]);
  *(float4*)&T1t[ob + 8]  = make_float4(acc[8], acc[9], acc[10], acc[11]);
  *(float4*)&T1t[ob + 12] = make_float4(acc[12], acc[13], acc[14], acc[15]);
}

// L[p] = clip((inp - S + g*R)/(g+1)); S = (inp - L)/(b+1); R = (1/Kc) * sum_{256 slices} Rpart
__global__ __launch_bounds__(256) void k_reduce_LS(const float* __restrict__ Rpart,
                                                   const float* __restrict__ inp,
                                                   const float* __restrict__ pg, const float* __restrict__ pb,
                                                   float* __restrict__ S, float* __restrict__ Ldst){
  __shared__ float red[8][32];
  int tid = threadIdx.x;
  int pi = tid & 31, sg = tid >> 5;
  int p = blockIdx.x * 32 + pi;
  float acc = 0.0f;
  #pragma unroll 4
  for (int s = sg * 32; s < sg * 32 + 32; s++) acc += Rpart[(size_t)s * 8192 + p];
  red[sg][pi] = acc;
  __syncthreads();
  if (tid < 32){
    float a = 0.0f;
    #pragma unroll
    for (int q = 0; q < 8; q++) a += red[q][pi];
    float R = a * (1.0f / 2592.0f);
    float g = pg[0], b = pb[0];
    float Ln = (inp[p] - S[p] + g * R) / (g + 1.0f);
    Ln = fminf(fmaxf(Ln, 0.0f), 1.0f);
    S[p] = (inp[p] - Ln) / (b + 1.0f);
    Ldst[p] = Ln;
  }
}

// raw gram: out[r1][r2] = dot(rows[r1], rows[r2]) over len4 float4s (row stride in floats)
__global__ __launch_bounds__(64) void k_gram(const float* __restrict__ rows, int stride, int len4,
                                             float* __restrict__ out){
  int e = blockIdx.x; int r1 = e >> 6, r2 = e & 63;
  if (r2 < r1) return;
  int lane = threadIdx.x;
  const float4* a = (const float4*)(rows + (size_t)r1 * stride);
  const float4* b = (const float4*)(rows + (size_t)r2 * stride);
  float acc = 0.0f;
  for (int p = lane; p < len4; p += 64){
    float4 x = a[p], y = b[p];
    acc = fmaf(x.x, y.x, acc); acc = fmaf(x.y, y.y, acc);
    acc = fmaf(x.z, y.z, acc); acc = fmaf(x.w, y.w, acc);
  }
  for (int off = 32; off; off >>= 1) acc += __shfl_down(acc, off, 64);
  if (lane == 0){ out[r1 * 64 + r2] = acc; out[r2 * 64 + r1] = acc; }
}

// Mt_new[sbase+s][p] = 2g * sum_{r<64} (sum_z T1t[r+64z][p]) * CmInv[r][sbase+s]
__global__ __launch_bounds__(256) void k_mn(const float* __restrict__ T1t, const float* __restrict__ CmInv,
                                            const float* __restrict__ pg, float* __restrict__ Mt){
  __shared__ float4 ci4[1024];
  int tid = threadIdx.x;
  const float4* g4 = (const float4*)CmInv;
  for (int t = tid; t < 1024; t += 256) ci4[t] = g4[t];
  __syncthreads();
  int p = blockIdx.x * 256 + tid;
  int sbase = blockIdx.y * 32;
  float g2 = 2.0f * pg[0];
  float acc[32];
  #pragma unroll
  for (int s = 0; s < 32; s++) acc[s] = 0.0f;
  for (int r = 0; r < 64; r++){
    float v = T1t[(size_t)r * 8192 + p] + T1t[(size_t)(r + 64) * 8192 + p]
            + T1t[(size_t)(r + 128) * 8192 + p] + T1t[(size_t)(r + 192) * 8192 + p];
    #pragma unroll
    for (int k = 0; k < 8; k++){
      float4 c = ci4[r * 16 + (sbase >> 2) + k];
      acc[4*k+0] = fmaf(v, c.x, acc[4*k+0]);
      acc[4*k+1] = fmaf(v, c.y, acc[4*k+1]);
      acc[4*k+2] = fmaf(v, c.z, acc[4*k+2]);
      acc[4*k+3] = fmaf(v, c.w, acc[4*k+3]);
    }
  }
  #pragma unroll
  for (int s = 0; s < 32; s++) Mt[(size_t)(sbase + s) * 8192 + p] = g2 * acc[s];
}

// T2part[hc][r][col] (+ fused inv(Cn) PHASE A as sentinel y==8)
__global__ __launch_bounds__(256) void k_conv_T2(const float* __restrict__ Lg,
                                                 const float* __restrict__ Mtg,
                                                 float* __restrict__ T2part,
                                                 const float* __restrict__ Gr,
                                                 const float* __restrict__ pg,
                                                 const float* __restrict__ pa,
                                                 float* __restrict__ state){
  __shared__ float Mi[128 * 68];
  __shared__ float4 Ls4[256];
  if (blockIdx.y == 8){
    if (blockIdx.x == 0 && threadIdx.x < 64)
      inv64_phaseA<48>(Gr, pg, pa, state, threadIdx.x);
    return;
  }
  int r = blockIdx.x, hc = blockIdx.y, tid = threadIdx.x;
  const float4* gm4 = (const float4*)(Mtg + (size_t)r * 8192);
  for (int t = tid; t < 2048; t += 256){
    float4 v4 = gm4[t];
    int row = t >> 4, cb = (t & 15) * 4;
    float* d = &Mi[row * 68 + cb];
    d[0] = v4.x; d[1] = v4.y; d[2] = v4.z; d[3] = v4.w;
  }
  const float4* gl4 = (const float4*)Lg;
  if (tid < 256){
    int c = tid >> 7, rem = tid & 127;
    Ls4[tid] = gl4[c * 1024 + hc * 128 + rem];
  }
  __syncthreads();
  if (tid >= 216) return;
  int kk = tid / 108, rest = tid % 108, ii = rest / 3, jj0 = (rest % 3) * 12;
  float acc[12];
  #pragma unroll
  for (int u = 0; u < 12; u++) acc[u] = 0.0f;
  #pragma unroll 1
  for (int c = 0; c < 2; c++){
    #pragma unroll 1
    for (int hl = 0; hl < 8; hl++){
      int h = hc * 8 + hl;
      const float* ib = &Mi[(((c + kk) & 1) * 64 + ((h + ii) & 63)) * 68];
      const float4* lrow = &Ls4[c * 128 + hl * 16];
      float v[16];
      {
        float4 t0 = *(const float4*)&ib[jj0];
        float4 t1 = *(const float4*)&ib[jj0 + 4];
        float4 t2 = *(const float4*)&ib[jj0 + 8];
        float4 t3 = *(const float4*)&ib[jj0 + 12];
        v[0]=t0.x; v[1]=t0.y; v[2]=t0.z; v[3]=t0.w;
        v[4]=t1.x; v[5]=t1.y; v[6]=t1.z; v[7]=t1.w;
        v[8]=t2.x; v[9]=t2.y; v[10]=t2.z; v[11]=t2.w;
        v[12]=t3.x; v[13]=t3.y; v[14]=t3.z; v[15]=t3.w;
      }
      #pragma unroll
      for (int wg = 0; wg < 16; wg++){
        float4 lv = lrow[wg];
        #pragma unroll
        for (int u = 0; u < 12; u++) acc[u] = fmaf(lv.x, v[(4*wg + 0 + u) & 15], acc[u]);
        #pragma unroll
        for (int u = 0; u < 12; u++) acc[u] = fmaf(lv.y, v[(4*wg + 1 + u) & 15], acc[u]);
        #pragma unroll
        for (int u = 0; u < 12; u++) acc[u] = fmaf(lv.z, v[(4*wg + 2 + u) & 15], acc[u]);
        #pragma unroll
        for (int u = 0; u < 12; u++) acc[u] = fmaf(lv.w, v[(4*wg + 3 + u) & 15], acc[u]);
        if (wg < 15){
          float4 nv = *(const float4*)&ib[(jj0 + 4*wg + 16) & 63];
          int s = (4*wg) & 15;
          v[s] = nv.x; v[s+1] = nv.y; v[s+2] = nv.z; v[s+3] = nv.w;
        }
      }
    }
  }
  #pragma unroll
  for (int u = 0; u < 12; u++){
    int col = kk * 1296 + (jj0 + u) * 36 + ii;
    T2part[((size_t)hc * 64 + r) * KC + col] = acc[u];
  }
}

// T2sum[t] = sum_hc T2part[hc*165888 + t]  (+ fused inv(Cn) PHASE B as sentinel block 648)
__global__ __launch_bounds__(256) void k_t2sum(const float* __restrict__ T2part, float* __restrict__ T2sum,
                                               const float* __restrict__ state, float* __restrict__ CnI){
  if (blockIdx.x == 648){
    if (threadIdx.x < 64)
      inv64_phaseB<48>(state, CnI, threadIdx.x);
    return;
  }
  int t = blockIdx.x * 256 + threadIdx.x;
  float s = 0.0f;
  #pragma unroll
  for (int hc = 0; hc < 8; hc++) s += T2part[(size_t)hc * 165888 + t];
  T2sum[t] = s;
}

// NtT[rr][d(col)] = 2g * sum_s CnInv[s][rr] * T2sum[s][col], rr in 16-chunk per blockIdx.y
__global__ __launch_bounds__(256) void k_nn(const float* __restrict__ T2sum, const float* __restrict__ CnInv,
                                            const float* __restrict__ pg,
                                            float* __restrict__ NtT){
  __shared__ float4 ci4[1024];
  int tid = threadIdx.x;
  const float4* g4 = (const float4*)CnInv;
  for (int t = tid; t < 1024; t += 256) ci4[t] = g4[t];
  __syncthreads();
  int col = blockIdx.x * 256 + tid;
  if (col >= KC) return;
  int rb = blockIdx.y * 16;
  float g2 = 2.0f * pg[0];
  float acc[16];
  #pragma unroll
  for (int rr = 0; rr < 16; rr++) acc[rr] = 0.0f;
  for (int s = 0; s < 64; s++){
    float tv = T2sum[(size_t)s * KC + col];
    #pragma unroll
    for (int k = 0; k < 4; k++){
      float4 c = ci4[s * 16 + (rb >> 2) + k];
      acc[4*k+0] = fmaf(tv, c.x, acc[4*k+0]);
      acc[4*k+1] = fmaf(tv, c.y, acc[4*k+1]);
      acc[4*k+2] = fmaf(tv, c.z, acc[4*k+2]);
      acc[4*k+3] = fmaf(tv, c.w, acc[4*k+3]);
    }
  }
  int kk = col / 1296, rest = col % 1296, jj = rest / 36, iv = rest % 36;
  int d = (kk * 36 + iv) * 36 + jj;
  #pragma unroll
  for (int rr = 0; rr < 16; rr++){
    NtT[(size_t)(rb + rr) * KCP + d] = g2 * acc[rr];
  }
}

extern "C" void kernel_launch(void* const* d_in, const int* in_sizes, int n_in,
                              void* d_out, int out_size, void* d_ws, size_t ws_size,
                              hipStream_t stream) {
  const float* inp = (const float*)d_in[0];
  const float* s0  = (const float*)d_in[1];
  const float* pa  = (const float*)d_in[2];
  const float* pb  = (const float*)d_in[3];
  const float* pg  = (const float*)d_in[4];
  float* ws  = (float*)d_ws;
  float* L   = ws + OFF_L;   float* S   = ws + OFF_S;    float* Mt  = ws + OFF_MT;
  float* NtT = ws + OFF_NTT; float* Big = ws + OFF_BIG;
  float* T2p = ws + OFF_BIG;              // aliased into Big (disjoint lifetimes)
  float* T2s = ws + OFF_BIG + 1327104u;   // aliased into Big
  float* Gr  = ws + OFF_GRAM;
  float* CmI = ws + OFF_CMI; float* CnI = ws + OFF_CNI;
  float* St  = ws + OFF_ST;
  float* out = (float*)d_out;

  k_init<<<2048, 256, 0, stream>>>(inp, s0, L, S, Mt, NtT);
  for (int step = 0; step < 5; step++){
    bool last = (step == 4);
    if (!last)
      k_gram<<<4096, 64, 0, stream>>>(NtT, KCP, KCP / 4, Gr);   // Cm raw = N@N^T (pad zeros)
    // conv_R grid z==4 (non-last steps) carries inv(Cm) PHASE A (pivots 0..32) -> state
    k_conv_R<<<dim3(64, 4, last ? 4 : 5), 128, 0, stream>>>(Mt, NtT, Big, Gr, pg, pa, St);
    k_reduce_LS<<<256, 256, 0, stream>>>(Big, inp, pg, pb, S, last ? out : L);
    if (last) break;
    // conv_T1 grid z==4 carries inv(Cm) PHASE B (pivots 32..64) -> CmI
    k_conv_T1<<<dim3(64, 4, 5), 128, 0, stream>>>(L, NtT, Big, St, CmI);
    k_mn<<<dim3(32, 2), 256, 0, stream>>>(Big, CmI, pg, Mt);
    k_gram<<<4096, 64, 0, stream>>>(Mt, 8192, 2048, Gr);        // Cn raw = Mn^T@Mn
    // conv_T2 grid y==8 carries inv(Cn) PHASE A (pivots 0..48) -> state
    k_conv_T2<<<dim3(64, 9), 256, 0, stream>>>(L, Mt, T2p, Gr, pg, pa, St);
    // t2sum block 648 carries inv(Cn) PHASE B (pivots 48..64) -> CnI
    k_t2sum<<<649, 256, 0, stream>>>(T2p, T2s, St, CnI);
    k_nn<<<dim3(11, 4), 256, 0, stream>>>(T2s, CnI, pg, NtT);
  }
}